// Round 1
// baseline (1473.826 us; speedup 1.0000x reference)
//
#include <hip/hip_runtime.h>
#include <hip/hip_bf16.h>

#define BB 2
#define SS 2048
#define INC 64
#define HIDN 512
#define NHH 8
#define HDD 64

// ---------------------------------------------------------------------------
// prep: transpose Wq/Wk/Wv into WallT (512 x 1536), Wo into WoT (512x512),
// concat biases into ball (1536)
// ---------------------------------------------------------------------------
__global__ __launch_bounds__(256) void prep_kernel(
    const float* __restrict__ Wq, const float* __restrict__ Wk_,
    const float* __restrict__ Wv_, const float* __restrict__ bq,
    const float* __restrict__ bk_, const float* __restrict__ bv_,
    const float* __restrict__ Wo, float* __restrict__ WallT,
    float* __restrict__ ball, float* __restrict__ WoT) {
  int i0 = blockIdx.x * 256 + threadIdx.x;
  int stride = gridDim.x * 256;
  for (int idx = i0; idx < 512 * 1536; idx += stride) {
    int k = idx / 1536, n = idx % 1536;
    float v;
    if (n < 512)       v = Wq[n * 512 + k];
    else if (n < 1024) v = Wk_[(n - 512) * 512 + k];
    else               v = Wv_[(n - 1024) * 512 + k];
    WallT[idx] = v;
  }
  for (int idx = i0; idx < 512 * 512; idx += stride) {
    WoT[idx] = Wo[(idx % 512) * 512 + (idx / 512)];
  }
  if (i0 < 1536) {
    float v;
    if (i0 < 512)       v = bq[i0];
    else if (i0 < 1024) v = bk_[i0 - 512];
    else                v = bv_[i0 - 1024];
    ball[i0] = v;
  }
}

// ---------------------------------------------------------------------------
// conv: h[b,s,c] = relu(conv{1,2,3}(x)) concat over channels. 8 s per block.
// ---------------------------------------------------------------------------
template <int KW, int OFF>
__device__ __forceinline__ void conv_channel(const float* __restrict__ w,
                                             const float* xs, float bias,
                                             float acc[8]) {
#pragma unroll
  for (int i = 0; i < 8; i++) acc[i] = bias;
  for (int ci = 0; ci < 64; ci++) {
    float xv[8 + KW - 1];
#pragma unroll
    for (int r = 0; r < 8 + KW - 1; r++) xv[r] = xs[(r + OFF) * 64 + ci];
#pragma unroll
    for (int k = 0; k < KW; k++) {
      float wv = w[ci * KW + k];
#pragma unroll
      for (int i = 0; i < 8; i++) acc[i] += xv[i + k] * wv;
    }
  }
}

__global__ __launch_bounds__(256) void conv_kernel(
    const float* __restrict__ x, const float* __restrict__ w1,
    const float* __restrict__ b1, const float* __restrict__ w2,
    const float* __restrict__ b2, const float* __restrict__ w3,
    const float* __restrict__ b3, float* __restrict__ h) {
  const int TS = 8;
  int blk = blockIdx.x;                 // 512 blocks
  int b = blk / (SS / TS);
  int s0 = (blk % (SS / TS)) * TS;
  __shared__ float xs[(TS + 6) * 64];   // rows s0-3 .. s0+TS+2
  int tid = threadIdx.x;
  for (int i = tid; i < (TS + 6) * 64; i += 256) {
    int row = i >> 6, ci = i & 63;
    int sgl = s0 + row - 3;
    xs[i] = (sgl >= 0 && sgl < SS) ? x[(b * SS + sgl) * 64 + ci] : 0.f;
  }
  __syncthreads();
  for (int c = tid; c < 512; c += 256) {
    float acc[8];
    if (c < 171) {
      conv_channel<3, 2>(w1 + c * (64 * 3), xs, b1[c], acc);
    } else if (c < 342) {
      conv_channel<5, 1>(w2 + (c - 171) * (64 * 5), xs, b2[c - 171], acc);
    } else {
      conv_channel<7, 0>(w3 + (c - 342) * (64 * 7), xs, b3[c - 342], acc);
    }
#pragma unroll
    for (int i = 0; i < 8; i++)
      h[(b * SS + s0 + i) * 512 + c] = fmaxf(acc[i], 0.f);
  }
}

// ---------------------------------------------------------------------------
// QKV gemm: C(4096 x 1536) = h(4096x512) @ WallT(512x1536) + ball,
// scattered into Q/K/V (B,NH,S,HD)
// ---------------------------------------------------------------------------
__global__ __launch_bounds__(256) void gemm_qkv(
    const float* __restrict__ A, const float* __restrict__ Bm,
    const float* __restrict__ bias, float* __restrict__ Qo,
    float* __restrict__ Ko, float* __restrict__ Vo) {
  int m0 = blockIdx.x * 64;
  int n0 = blockIdx.y * 64;
  int tid = threadIdx.x;
  __shared__ float As[16][68];  // [k][m]
  __shared__ float Bs[16][68];  // [k][n]
  int tm = tid >> 4, tn = tid & 15;
  int ra = tid >> 2, ca = (tid & 3) * 4;
  int rb = tid >> 4, cb = (tid & 15) * 4;
  float acc[4][4] = {};
  for (int k0 = 0; k0 < 512; k0 += 16) {
    float4 av = *(const float4*)(A + (m0 + ra) * 512 + k0 + ca);
    float4 bv = *(const float4*)(Bm + (k0 + rb) * 1536 + n0 + cb);
    As[ca + 0][ra] = av.x; As[ca + 1][ra] = av.y;
    As[ca + 2][ra] = av.z; As[ca + 3][ra] = av.w;
    *(float4*)&Bs[rb][cb] = bv;
    __syncthreads();
#pragma unroll
    for (int k = 0; k < 16; k++) {
      float4 a4 = *(const float4*)&As[k][tm * 4];
      float4 b4 = *(const float4*)&Bs[k][tn * 4];
      float av_[4] = {a4.x, a4.y, a4.z, a4.w};
      float bv_[4] = {b4.x, b4.y, b4.z, b4.w};
#pragma unroll
      for (int i = 0; i < 4; i++)
#pragma unroll
        for (int j = 0; j < 4; j++) acc[i][j] += av_[i] * bv_[j];
    }
    __syncthreads();
  }
  int which = n0 >> 9;
  int head = (n0 >> 6) & 7;
  float* dst = which == 0 ? Qo : (which == 1 ? Ko : Vo);
  float bjs[4];
#pragma unroll
  for (int j = 0; j < 4; j++) bjs[j] = bias[n0 + tn * 4 + j];
#pragma unroll
  for (int i = 0; i < 4; i++) {
    int m = m0 + tm * 4 + i;
    int bb = m >> 11, s = m & 2047;
    float* dp = dst + ((bb * 8 + head) * 2048 + s) * 64 + tn * 4;
    float4 o4 = make_float4(acc[i][0] + bjs[0], acc[i][1] + bjs[1],
                            acc[i][2] + bjs[2], acc[i][3] + bjs[3]);
    *(float4*)dp = o4;
  }
}

// ---------------------------------------------------------------------------
// Kp (transposed, B,NH,R,S) and Vp (B,NH,S,R) projections
// ---------------------------------------------------------------------------
__global__ __launch_bounds__(256) void kpvp_kernel(
    const float* __restrict__ K, const float* __restrict__ V,
    const float* __restrict__ Wkp, const float* __restrict__ bkp,
    const float* __restrict__ Wvp, const float* __restrict__ bvp,
    float* __restrict__ KpT, float* __restrict__ Vp) {
  int bh = blockIdx.x >> 4;            // 256 blocks: B*NH * (S/128)
  int k0 = (blockIdx.x & 15) * 128;
  int tid = threadIdx.x;
  __shared__ float tile[128][65];
  __shared__ float Wb[64][65];
  // ---- phase 1: KpT ----
  for (int i = tid; i < 128 * 64; i += 256)
    tile[i >> 6][i & 63] = K[(bh * 2048 + k0 + (i >> 6)) * 64 + (i & 63)];
  for (int i = tid; i < 4096; i += 256) Wb[i >> 6][i & 63] = Wkp[i];
  __syncthreads();
  {
    int kl = tid & 63, rb = (tid >> 6) * 16;
    for (int half = 0; half < 2; half++) {
      int kk = kl + half * 64;
      for (int ri = 0; ri < 16; ri++) {
        int r = rb + ri;
        float acc = bkp[r];
#pragma unroll 8
        for (int d = 0; d < 64; d++) acc += tile[kk][d] * Wb[r][d];
        KpT[(bh * 64 + r) * 2048 + k0 + kk] = acc;
      }
    }
  }
  __syncthreads();
  // ---- phase 2: Vp ----
  for (int i = tid; i < 128 * 64; i += 256)
    tile[i >> 6][i & 63] = V[(bh * 2048 + k0 + (i >> 6)) * 64 + (i & 63)];
  for (int i = tid; i < 4096; i += 256) Wb[i >> 6][i & 63] = Wvp[i];
  __syncthreads();
  {
    int r = tid & 63, kb = tid >> 6;
    for (int ri = 0; ri < 32; ri++) {
      int kk = kb + ri * 4;
      float acc = bvp[r];
#pragma unroll 8
      for (int d = 0; d < 64; d++) acc += tile[kk][d] * Wb[r][d];
      Vp[(bh * 2048 + k0 + kk) * 64 + r] = acc;
    }
  }
}

// ---------------------------------------------------------------------------
// local windowed attention: one wave per query
// ---------------------------------------------------------------------------
__global__ __launch_bounds__(256) void local_attn(
    const float* __restrict__ Q, const float* __restrict__ K,
    const float* __restrict__ V, float* __restrict__ ctxl) {
  int idx = blockIdx.x * 4 + (threadIdx.x >> 6);  // global query over B*NH*S
  int lane = threadIdx.x & 63;
  int bh = idx >> 11;
  int s = idx & 2047;
  float qd = Q[idx * 64 + lane];
  float sc[5];
  bool ok[5];
#pragma unroll
  for (int j = 0; j < 5; j++) {
    int sj = s + j - 2;
    ok[j] = (sj >= 0 && sj < SS);
    float p = ok[j] ? qd * K[(bh * 2048 + sj) * 64 + lane] : 0.f;
    p += __shfl_xor(p, 1);  p += __shfl_xor(p, 2);  p += __shfl_xor(p, 4);
    p += __shfl_xor(p, 8);  p += __shfl_xor(p, 16); p += __shfl_xor(p, 32);
    sc[j] = p * 0.125f;
  }
  float m = -3.0e38f;
#pragma unroll
  for (int j = 0; j < 5; j++)
    if (ok[j]) m = fmaxf(m, sc[j]);
  float e[5], l = 0.f;
#pragma unroll
  for (int j = 0; j < 5; j++) {
    e[j] = ok[j] ? expf(sc[j] - m) : 0.f;
    l += e[j];
  }
  float inv = 1.f / l;
  float o = 0.f;
#pragma unroll
  for (int j = 0; j < 5; j++) {
    int sj = s + j - 2;
    if (ok[j]) o += e[j] * inv * V[(bh * 2048 + sj) * 64 + lane];
  }
  ctxl[idx * 64 + lane] = o;
}

// ---------------------------------------------------------------------------
// global sparse attention: scores vs KpT, fused running top-16, softmax,
// Vp gather, Wvp projection, combine with local -> ctxc (B,S,512)
// ---------------------------------------------------------------------------
#define QT 32
__global__ __launch_bounds__(256) void global_attn(
    const float* __restrict__ Q, const float* __restrict__ KpT,
    const float* __restrict__ Vp, const float* __restrict__ Wvp,
    const float* __restrict__ bvp, const float* __restrict__ ctxl,
    float* __restrict__ ctxc) {
  int bh = blockIdx.x >> 6;            // 1024 blocks
  int q0 = (blockIdx.x & 63) * QT;
  int b = bh >> 3, hh = bh & 7;
  int tid = threadIdx.x;
  __shared__ float QsT[64][32];        // [d][q]
  __shared__ float KtT[64][128];       // [d][k]  (reused as spr later)
  __shared__ float Sc[QT][132];
  __shared__ float topv[QT][16];
  __shared__ int   topi[QT][16];
  __shared__ float tw[QT][16];
  for (int i = tid; i < QT * 64; i += 256) {
    int qq = i >> 6, d = i & 63;
    QsT[d][qq] = Q[(bh * 2048 + q0 + qq) * 64 + d];
  }
  for (int i = tid; i < QT * 16; i += 256) {
    topv[i >> 4][i & 15] = -3.0e38f;
    topi[i >> 4][i & 15] = 0;
  }
  __syncthreads();
  int q4 = (tid >> 5) * 4;
  int k4 = (tid & 31) * 4;
  for (int kt = 0; kt < 16; kt++) {
    int k0 = kt * 128;
    for (int i = tid; i < 64 * 128; i += 256) {
      int d = i >> 7, kk = i & 127;
      KtT[d][kk] = KpT[(bh * 64 + d) * 2048 + k0 + kk];
    }
    __syncthreads();
    float acc[4][4] = {};
#pragma unroll 8
    for (int d = 0; d < 64; d++) {
      float4 qa = *(const float4*)&QsT[d][q4];
      float4 kb = *(const float4*)&KtT[d][k4];
      float qv[4] = {qa.x, qa.y, qa.z, qa.w};
      float kv[4] = {kb.x, kb.y, kb.z, kb.w};
#pragma unroll
      for (int i = 0; i < 4; i++)
#pragma unroll
        for (int j = 0; j < 4; j++) acc[i][j] += qv[i] * kv[j];
    }
#pragma unroll
    for (int i = 0; i < 4; i++) {
      float4 s4 = make_float4(acc[i][0] * 0.125f, acc[i][1] * 0.125f,
                              acc[i][2] * 0.125f, acc[i][3] * 0.125f);
      *(float4*)&Sc[q4 + i][k4] = s4;
    }
    __syncthreads();
    if (tid < QT) {
      int q = tid;
      float vmin = topv[q][15];
      for (int kk = 0; kk < 128; kk++) {
        float v = Sc[q][kk];
        if (v > vmin) {
          int p = 15;
          while (p > 0 && topv[q][p - 1] < v) {
            topv[q][p] = topv[q][p - 1];
            topi[q][p] = topi[q][p - 1];
            p--;
          }
          topv[q][p] = v;
          topi[q][p] = k0 + kk;
          vmin = topv[q][15];
        }
      }
    }
    __syncthreads();
  }
  if (tid < QT) {
    int q = tid;
    float m = topv[q][0];
    float ev[16], l = 0.f;
#pragma unroll
    for (int j = 0; j < 16; j++) {
      ev[j] = expf(topv[q][j] - m);
      l += ev[j];
    }
    float inv = 1.f / l;
#pragma unroll
    for (int j = 0; j < 16; j++) tw[q][j] = ev[j] * inv;
  }
  __syncthreads();
  float* spr = &KtT[0][0];  // QT*68 floats, aliases KtT (done with it)
  {
    int q = tid >> 3, rl = (tid & 7) * 8;
    float accr[8] = {};
#pragma unroll
    for (int j = 0; j < 16; j++) {
      float w = tw[q][j];
      const float* vrow = Vp + (bh * 2048 + topi[q][j]) * 64 + rl;
#pragma unroll
      for (int u = 0; u < 8; u++) accr[u] += w * vrow[u];
    }
#pragma unroll
    for (int u = 0; u < 8; u++) spr[q * 68 + rl + u] = accr[u];
  }
  __syncthreads();
  {
    int q = tid >> 3, jb = (tid & 7) * 8;
    int s = q0 + q;
#pragma unroll
    for (int u = 0; u < 8; u++) {
      int j = jb + u;
      float acc = bvp[j];
#pragma unroll 8
      for (int r = 0; r < 64; r++) acc += spr[q * 68 + r] * Wvp[j * 64 + r];
      float lv = ctxl[(bh * 2048 + s) * 64 + j];
      ctxc[(b * 2048 + s) * 512 + hh * 64 + j] = 0.5f * (lv + acc);
    }
  }
}

// ---------------------------------------------------------------------------
// Wo gemm + bias + residual(h) -> d_out (pre-layernorm)
// ---------------------------------------------------------------------------
__global__ __launch_bounds__(256) void gemm_wo(
    const float* __restrict__ A, const float* __restrict__ Bm,
    const float* __restrict__ bo, const float* __restrict__ h,
    float* __restrict__ outp) {
  int m0 = blockIdx.x * 64;
  int n0 = blockIdx.y * 64;
  int tid = threadIdx.x;
  __shared__ float As[16][68];
  __shared__ float Bs[16][68];
  int tm = tid >> 4, tn = tid & 15;
  int ra = tid >> 2, ca = (tid & 3) * 4;
  int rb = tid >> 4, cb = (tid & 15) * 4;
  float acc[4][4] = {};
  for (int k0 = 0; k0 < 512; k0 += 16) {
    float4 av = *(const float4*)(A + (m0 + ra) * 512 + k0 + ca);
    float4 bv = *(const float4*)(Bm + (k0 + rb) * 512 + n0 + cb);
    As[ca + 0][ra] = av.x; As[ca + 1][ra] = av.y;
    As[ca + 2][ra] = av.z; As[ca + 3][ra] = av.w;
    *(float4*)&Bs[rb][cb] = bv;
    __syncthreads();
#pragma unroll
    for (int k = 0; k < 16; k++) {
      float4 a4 = *(const float4*)&As[k][tm * 4];
      float4 b4 = *(const float4*)&Bs[k][tn * 4];
      float av_[4] = {a4.x, a4.y, a4.z, a4.w};
      float bv_[4] = {b4.x, b4.y, b4.z, b4.w};
#pragma unroll
      for (int i = 0; i < 4; i++)
#pragma unroll
        for (int j = 0; j < 4; j++) acc[i][j] += av_[i] * bv_[j];
    }
    __syncthreads();
  }
  float bjs[4];
#pragma unroll
  for (int j = 0; j < 4; j++) bjs[j] = bo[n0 + tn * 4 + j];
#pragma unroll
  for (int i = 0; i < 4; i++) {
    int m = m0 + tm * 4 + i;
    const float* hp = h + m * 512 + n0 + tn * 4;
    float4 h4 = *(const float4*)hp;
    float4 o4 = make_float4(acc[i][0] + bjs[0] + h4.x,
                            acc[i][1] + bjs[1] + h4.y,
                            acc[i][2] + bjs[2] + h4.z,
                            acc[i][3] + bjs[3] + h4.w);
    *(float4*)(outp + m * 512 + n0 + tn * 4) = o4;
  }
}

// ---------------------------------------------------------------------------
// layernorm in place on d_out, one block per row
// ---------------------------------------------------------------------------
__global__ __launch_bounds__(256) void ln_kernel(float* __restrict__ o,
                                                 const float* __restrict__ g,
                                                 const float* __restrict__ bb) {
  int row = blockIdx.x;
  int tid = threadIdx.x;
  float v0 = o[row * 512 + tid];
  float v1 = o[row * 512 + 256 + tid];
  float s = v0 + v1;
  float s2 = v0 * v0 + v1 * v1;
#pragma unroll
  for (int off = 1; off < 64; off <<= 1) {
    s += __shfl_xor(s, off);
    s2 += __shfl_xor(s2, off);
  }
  __shared__ float ps[4], ps2[4];
  int w = tid >> 6;
  if ((tid & 63) == 0) { ps[w] = s; ps2[w] = s2; }
  __syncthreads();
  float S = ps[0] + ps[1] + ps[2] + ps[3];
  float S2 = ps2[0] + ps2[1] + ps2[2] + ps2[3];
  float mu = S * (1.f / 512.f);
  float var = S2 * (1.f / 512.f) - mu * mu;
  float inv = rsqrtf(var + 1e-5f);
  o[row * 512 + tid] = (v0 - mu) * inv * g[tid] + bb[tid];
  o[row * 512 + 256 + tid] = (v1 - mu) * inv * g[tid + 256] + bb[tid + 256];
}

// ---------------------------------------------------------------------------
extern "C" void kernel_launch(void* const* d_in, const int* in_sizes, int n_in,
                              void* d_out, int out_size, void* d_ws,
                              size_t ws_size, hipStream_t stream) {
  const float* x   = (const float*)d_in[0];
  const float* w1  = (const float*)d_in[1];
  const float* b1  = (const float*)d_in[2];
  const float* w2  = (const float*)d_in[3];
  const float* b2  = (const float*)d_in[4];
  const float* w3  = (const float*)d_in[5];
  const float* b3  = (const float*)d_in[6];
  const float* Wq  = (const float*)d_in[7];
  const float* bq  = (const float*)d_in[8];
  const float* Wk  = (const float*)d_in[9];
  const float* bk  = (const float*)d_in[10];
  const float* Wv  = (const float*)d_in[11];
  const float* bv  = (const float*)d_in[12];
  const float* Wkp = (const float*)d_in[13];
  const float* bkp = (const float*)d_in[14];
  const float* Wvp = (const float*)d_in[15];
  const float* bvp = (const float*)d_in[16];
  const float* Wo  = (const float*)d_in[17];
  const float* bo  = (const float*)d_in[18];
  const float* lng = (const float*)d_in[19];
  const float* lnb = (const float*)d_in[20];

  float* ws    = (float*)d_ws;
  float* WallT = ws;                     // 786432
  float* ball  = WallT + 786432;         // 1536
  float* WoT   = ball + 1536;            // 262144
  float* h     = WoT + 262144;           // 2097152 each below
  float* Qb    = h + 2097152;
  float* Kb    = Qb + 2097152;
  float* Vb    = Kb + 2097152;
  float* KpT   = Vb + 2097152;
  float* Vpb   = KpT + 2097152;
  float* ctxl  = Vpb + 2097152;
  float* ctxc  = ctxl + 2097152;
  float* outF  = (float*)d_out;

  prep_kernel<<<512, 256, 0, stream>>>(Wq, Wk, Wv, bq, bk, bv, Wo, WallT, ball,
                                       WoT);
  conv_kernel<<<512, 256, 0, stream>>>(x, w1, b1, w2, b2, w3, b3, h);
  {
    dim3 g(64, 24);
    gemm_qkv<<<g, 256, 0, stream>>>(h, WallT, ball, Qb, Kb, Vb);
  }
  kpvp_kernel<<<256, 256, 0, stream>>>(Kb, Vb, Wkp, bkp, Wvp, bvp, KpT, Vpb);
  local_attn<<<8192, 256, 0, stream>>>(Qb, Kb, Vb, ctxl);
  global_attn<<<1024, 256, 0, stream>>>(Qb, KpT, Vpb, Wvp, bvp, ctxl, ctxc);
  {
    dim3 g(64, 8);
    gemm_wo<<<g, 256, 0, stream>>>(ctxc, WoT, bo, h, outF);
  }
  ln_kernel<<<4096, 256, 0, stream>>>(outF, lng, lnb);
}

// Round 2
// 956.791 us; speedup vs baseline: 1.5404x; 1.5404x over previous
//
#include <hip/hip_runtime.h>
#include <hip/hip_bf16.h>

#define BB 2
#define SS 2048
#define INC 64
#define HIDN 512
#define NHH 8
#define HDD 64

// ---------------------------------------------------------------------------
// prep: transpose Wq/Wk/Wv into WallT (512 x 1536), Wo into WoT (512x512),
// concat biases into ball (1536)
// ---------------------------------------------------------------------------
__global__ __launch_bounds__(256) void prep_kernel(
    const float* __restrict__ Wq, const float* __restrict__ Wk_,
    const float* __restrict__ Wv_, const float* __restrict__ bq,
    const float* __restrict__ bk_, const float* __restrict__ bv_,
    const float* __restrict__ Wo, float* __restrict__ WallT,
    float* __restrict__ ball, float* __restrict__ WoT) {
  int i0 = blockIdx.x * 256 + threadIdx.x;
  int stride = gridDim.x * 256;
  for (int idx = i0; idx < 512 * 1536; idx += stride) {
    int k = idx / 1536, n = idx % 1536;
    float v;
    if (n < 512)       v = Wq[n * 512 + k];
    else if (n < 1024) v = Wk_[(n - 512) * 512 + k];
    else               v = Wv_[(n - 1024) * 512 + k];
    WallT[idx] = v;
  }
  for (int idx = i0; idx < 512 * 512; idx += stride) {
    WoT[idx] = Wo[(idx % 512) * 512 + (idx / 512)];
  }
  if (i0 < 1536) {
    float v;
    if (i0 < 512)       v = bq[i0];
    else if (i0 < 1024) v = bk_[i0 - 512];
    else                v = bv_[i0 - 1024];
    ball[i0] = v;
  }
}

// ---------------------------------------------------------------------------
// conv: h[b,s,c] = relu(conv{1,2,3}(x)) concat over channels. 8 s per block.
// ---------------------------------------------------------------------------
template <int KW, int OFF>
__device__ __forceinline__ void conv_channel(const float* __restrict__ w,
                                             const float* xs, float bias,
                                             float acc[8]) {
#pragma unroll
  for (int i = 0; i < 8; i++) acc[i] = bias;
  for (int ci = 0; ci < 64; ci++) {
    float xv[8 + KW - 1];
#pragma unroll
    for (int r = 0; r < 8 + KW - 1; r++) xv[r] = xs[(r + OFF) * 64 + ci];
#pragma unroll
    for (int k = 0; k < KW; k++) {
      float wv = w[ci * KW + k];
#pragma unroll
      for (int i = 0; i < 8; i++) acc[i] += xv[i + k] * wv;
    }
  }
}

__global__ __launch_bounds__(256) void conv_kernel(
    const float* __restrict__ x, const float* __restrict__ w1,
    const float* __restrict__ b1, const float* __restrict__ w2,
    const float* __restrict__ b2, const float* __restrict__ w3,
    const float* __restrict__ b3, float* __restrict__ h) {
  const int TS = 8;
  int blk = blockIdx.x;                 // 512 blocks
  int b = blk / (SS / TS);
  int s0 = (blk % (SS / TS)) * TS;
  __shared__ float xs[(TS + 6) * 64];   // rows s0-3 .. s0+TS+2
  int tid = threadIdx.x;
  for (int i = tid; i < (TS + 6) * 64; i += 256) {
    int row = i >> 6, ci = i & 63;
    int sgl = s0 + row - 3;
    xs[i] = (sgl >= 0 && sgl < SS) ? x[(b * SS + sgl) * 64 + ci] : 0.f;
  }
  __syncthreads();
  for (int c = tid; c < 512; c += 256) {
    float acc[8];
    if (c < 171) {
      conv_channel<3, 2>(w1 + c * (64 * 3), xs, b1[c], acc);
    } else if (c < 342) {
      conv_channel<5, 1>(w2 + (c - 171) * (64 * 5), xs, b2[c - 171], acc);
    } else {
      conv_channel<7, 0>(w3 + (c - 342) * (64 * 7), xs, b3[c - 342], acc);
    }
#pragma unroll
    for (int i = 0; i < 8; i++)
      h[(b * SS + s0 + i) * 512 + c] = fmaxf(acc[i], 0.f);
  }
}

// ---------------------------------------------------------------------------
// QKV gemm: C(4096 x 1536) = h(4096x512) @ WallT(512x1536) + ball,
// scattered into Q/K/V (B,NH,S,HD)
// ---------------------------------------------------------------------------
__global__ __launch_bounds__(256) void gemm_qkv(
    const float* __restrict__ A, const float* __restrict__ Bm,
    const float* __restrict__ bias, float* __restrict__ Qo,
    float* __restrict__ Ko, float* __restrict__ Vo) {
  int m0 = blockIdx.x * 64;
  int n0 = blockIdx.y * 64;
  int tid = threadIdx.x;
  __shared__ float As[16][68];  // [k][m]
  __shared__ float Bs[16][68];  // [k][n]
  int tm = tid >> 4, tn = tid & 15;
  int ra = tid >> 2, ca = (tid & 3) * 4;
  int rb = tid >> 4, cb = (tid & 15) * 4;
  float acc[4][4] = {};
  for (int k0 = 0; k0 < 512; k0 += 16) {
    float4 av = *(const float4*)(A + (m0 + ra) * 512 + k0 + ca);
    float4 bv = *(const float4*)(Bm + (k0 + rb) * 1536 + n0 + cb);
    As[ca + 0][ra] = av.x; As[ca + 1][ra] = av.y;
    As[ca + 2][ra] = av.z; As[ca + 3][ra] = av.w;
    *(float4*)&Bs[rb][cb] = bv;
    __syncthreads();
#pragma unroll
    for (int k = 0; k < 16; k++) {
      float4 a4 = *(const float4*)&As[k][tm * 4];
      float4 b4 = *(const float4*)&Bs[k][tn * 4];
      float av_[4] = {a4.x, a4.y, a4.z, a4.w};
      float bv_[4] = {b4.x, b4.y, b4.z, b4.w};
#pragma unroll
      for (int i = 0; i < 4; i++)
#pragma unroll
        for (int j = 0; j < 4; j++) acc[i][j] += av_[i] * bv_[j];
    }
    __syncthreads();
  }
  int which = n0 >> 9;
  int head = (n0 >> 6) & 7;
  float* dst = which == 0 ? Qo : (which == 1 ? Ko : Vo);
  float bjs[4];
#pragma unroll
  for (int j = 0; j < 4; j++) bjs[j] = bias[n0 + tn * 4 + j];
#pragma unroll
  for (int i = 0; i < 4; i++) {
    int m = m0 + tm * 4 + i;
    int bb = m >> 11, s = m & 2047;
    float* dp = dst + ((bb * 8 + head) * 2048 + s) * 64 + tn * 4;
    float4 o4 = make_float4(acc[i][0] + bjs[0], acc[i][1] + bjs[1],
                            acc[i][2] + bjs[2], acc[i][3] + bjs[3]);
    *(float4*)dp = o4;
  }
}

// ---------------------------------------------------------------------------
// Kp (transposed, B,NH,R,S) and Vp (B,NH,S,R) projections
// ---------------------------------------------------------------------------
__global__ __launch_bounds__(256) void kpvp_kernel(
    const float* __restrict__ K, const float* __restrict__ V,
    const float* __restrict__ Wkp, const float* __restrict__ bkp,
    const float* __restrict__ Wvp, const float* __restrict__ bvp,
    float* __restrict__ KpT, float* __restrict__ Vp) {
  int bh = blockIdx.x >> 4;            // 256 blocks: B*NH * (S/128)
  int k0 = (blockIdx.x & 15) * 128;
  int tid = threadIdx.x;
  __shared__ float tile[128][65];
  __shared__ float Wb[64][65];
  // ---- phase 1: KpT ----
  for (int i = tid; i < 128 * 64; i += 256)
    tile[i >> 6][i & 63] = K[(bh * 2048 + k0 + (i >> 6)) * 64 + (i & 63)];
  for (int i = tid; i < 4096; i += 256) Wb[i >> 6][i & 63] = Wkp[i];
  __syncthreads();
  {
    int kl = tid & 63, rb = (tid >> 6) * 16;
    for (int half = 0; half < 2; half++) {
      int kk = kl + half * 64;
      for (int ri = 0; ri < 16; ri++) {
        int r = rb + ri;
        float acc = bkp[r];
#pragma unroll 8
        for (int d = 0; d < 64; d++) acc += tile[kk][d] * Wb[r][d];
        KpT[(bh * 64 + r) * 2048 + k0 + kk] = acc;
      }
    }
  }
  __syncthreads();
  // ---- phase 2: Vp ----
  for (int i = tid; i < 128 * 64; i += 256)
    tile[i >> 6][i & 63] = V[(bh * 2048 + k0 + (i >> 6)) * 64 + (i & 63)];
  for (int i = tid; i < 4096; i += 256) Wb[i >> 6][i & 63] = Wvp[i];
  __syncthreads();
  {
    int r = tid & 63, kb = tid >> 6;
    for (int ri = 0; ri < 32; ri++) {
      int kk = kb + ri * 4;
      float acc = bvp[r];
#pragma unroll 8
      for (int d = 0; d < 64; d++) acc += tile[kk][d] * Wb[r][d];
      Vp[(bh * 2048 + k0 + kk) * 64 + r] = acc;
    }
  }
}

// ---------------------------------------------------------------------------
// local windowed attention: one wave per query
// ---------------------------------------------------------------------------
__global__ __launch_bounds__(256) void local_attn(
    const float* __restrict__ Q, const float* __restrict__ K,
    const float* __restrict__ V, float* __restrict__ ctxl) {
  int idx = blockIdx.x * 4 + (threadIdx.x >> 6);  // global query over B*NH*S
  int lane = threadIdx.x & 63;
  int bh = idx >> 11;
  int s = idx & 2047;
  float qd = Q[idx * 64 + lane];
  float sc[5];
  bool ok[5];
#pragma unroll
  for (int j = 0; j < 5; j++) {
    int sj = s + j - 2;
    ok[j] = (sj >= 0 && sj < SS);
    float p = ok[j] ? qd * K[(bh * 2048 + sj) * 64 + lane] : 0.f;
    p += __shfl_xor(p, 1);  p += __shfl_xor(p, 2);  p += __shfl_xor(p, 4);
    p += __shfl_xor(p, 8);  p += __shfl_xor(p, 16); p += __shfl_xor(p, 32);
    sc[j] = p * 0.125f;
  }
  float m = -3.0e38f;
#pragma unroll
  for (int j = 0; j < 5; j++)
    if (ok[j]) m = fmaxf(m, sc[j]);
  float e[5], l = 0.f;
#pragma unroll
  for (int j = 0; j < 5; j++) {
    e[j] = ok[j] ? expf(sc[j] - m) : 0.f;
    l += e[j];
  }
  float inv = 1.f / l;
  float o = 0.f;
#pragma unroll
  for (int j = 0; j < 5; j++) {
    int sj = s + j - 2;
    if (ok[j]) o += e[j] * inv * V[(bh * 2048 + sj) * 64 + lane];
  }
  ctxl[idx * 64 + lane] = o;
}

// ---------------------------------------------------------------------------
// global sparse attention: scores vs KpT, fused PARALLEL-FILTERED running
// top-16, softmax, Vp gather, Wvp projection, combine with local -> ctxc
// ---------------------------------------------------------------------------
#define QT 32
__global__ __launch_bounds__(256) void global_attn(
    const float* __restrict__ Q, const float* __restrict__ KpT,
    const float* __restrict__ Vp, const float* __restrict__ Wvp,
    const float* __restrict__ bvp, const float* __restrict__ ctxl,
    float* __restrict__ ctxc) {
  int bh = blockIdx.x >> 6;            // 1024 blocks
  int q0 = (blockIdx.x & 63) * QT;
  int b = bh >> 3, hh = bh & 7;
  int tid = threadIdx.x;
  __shared__ float QsT[64][32];        // [d][q]
  __shared__ float KtT[64][128];       // [d][k]  (reused as spr later)
  __shared__ float Sc[QT][132];
  __shared__ float topv[QT][17];       // stride 17: leaders conflict-free
  __shared__ int   topi[QT][17];
  __shared__ float tw[QT][17];
  __shared__ unsigned short smask[QT][8];
  for (int i = tid; i < QT * 64; i += 256) {
    int qq = i >> 6, d = i & 63;
    QsT[d][qq] = Q[(bh * 2048 + q0 + qq) * 64 + d];
  }
  for (int i = tid; i < QT * 16; i += 256) {
    topv[i >> 4][i & 15] = -3.0e38f;
    topi[i >> 4][i & 15] = 0;
  }
  __syncthreads();
  int q4 = (tid >> 5) * 4;
  int k4 = (tid & 31) * 4;
  int qg = tid >> 3;        // group: one of 32 queries
  int lg = tid & 7;         // lane within group
  for (int kt = 0; kt < 16; kt++) {
    int k0 = kt * 128;
    for (int i = tid; i < 64 * 128; i += 256) {
      int d = i >> 7, kk = i & 127;
      KtT[d][kk] = KpT[(bh * 64 + d) * 2048 + k0 + kk];
    }
    __syncthreads();
    float acc[4][4] = {};
#pragma unroll 8
    for (int d = 0; d < 64; d++) {
      float4 qa = *(const float4*)&QsT[d][q4];
      float4 kb = *(const float4*)&KtT[d][k4];
      float qv[4] = {qa.x, qa.y, qa.z, qa.w};
      float kv[4] = {kb.x, kb.y, kb.z, kb.w};
#pragma unroll
      for (int i = 0; i < 4; i++)
#pragma unroll
        for (int j = 0; j < 4; j++) acc[i][j] += qv[i] * kv[j];
    }
#pragma unroll
    for (int i = 0; i < 4; i++) {
      float4 s4 = make_float4(acc[i][0] * 0.125f, acc[i][1] * 0.125f,
                              acc[i][2] * 0.125f, acc[i][3] * 0.125f);
      *(float4*)&Sc[q4 + i][k4] = s4;
    }
    __syncthreads();
    // ---- parallel filter: 8 threads/query, 16 keys each ----
    {
      float vmin = topv[qg][15];  // only rises; stale -> false positives only
      const float* row = &Sc[qg][lg * 16];
      unsigned m = 0;
#pragma unroll
      for (int u = 0; u < 4; u++) {
        float4 v4 = *(const float4*)(row + u * 4);
        m |= (v4.x > vmin ? 1u : 0u) << (u * 4 + 0);
        m |= (v4.y > vmin ? 1u : 0u) << (u * 4 + 1);
        m |= (v4.z > vmin ? 1u : 0u) << (u * 4 + 2);
        m |= (v4.w > vmin ? 1u : 0u) << (u * 4 + 3);
      }
      smask[qg][lg] = (unsigned short)m;
    }
    __syncthreads();
    // ---- leader inserts survivors in ascending key order ----
    if (lg == 0) {
      float vmin = topv[qg][15];
#pragma unroll 1
      for (int t = 0; t < 8; t++) {
        unsigned m = smask[qg][t];
        while (m) {
          int j = __ffs(m) - 1;
          m &= m - 1;
          int kk = t * 16 + j;
          float v = Sc[qg][kk];
          if (v > vmin) {
            int p = 15;
            while (p > 0 && topv[qg][p - 1] < v) {
              topv[qg][p] = topv[qg][p - 1];
              topi[qg][p] = topi[qg][p - 1];
              p--;
            }
            topv[qg][p] = v;
            topi[qg][p] = k0 + kk;
            vmin = topv[qg][15];
          }
        }
      }
    }
    __syncthreads();
  }
  if (tid < QT) {
    int q = tid;
    float m = topv[q][0];
    float ev[16], l = 0.f;
#pragma unroll
    for (int j = 0; j < 16; j++) {
      ev[j] = expf(topv[q][j] - m);
      l += ev[j];
    }
    float inv = 1.f / l;
#pragma unroll
    for (int j = 0; j < 16; j++) tw[q][j] = ev[j] * inv;
  }
  __syncthreads();
  float* spr = &KtT[0][0];  // QT*68 floats, aliases KtT (done with it)
  {
    int q = tid >> 3, rl = (tid & 7) * 8;
    float accr[8] = {};
#pragma unroll
    for (int j = 0; j < 16; j++) {
      float w = tw[q][j];
      const float* vrow = Vp + (bh * 2048 + topi[q][j]) * 64 + rl;
#pragma unroll
      for (int u = 0; u < 8; u++) accr[u] += w * vrow[u];
    }
#pragma unroll
    for (int u = 0; u < 8; u++) spr[q * 68 + rl + u] = accr[u];
  }
  __syncthreads();
  {
    int q = tid >> 3, jb = (tid & 7) * 8;
    int s = q0 + q;
#pragma unroll
    for (int u = 0; u < 8; u++) {
      int j = jb + u;
      float acc = bvp[j];
#pragma unroll 8
      for (int r = 0; r < 64; r++) acc += spr[q * 68 + r] * Wvp[j * 64 + r];
      float lv = ctxl[(bh * 2048 + s) * 64 + j];
      ctxc[(b * 2048 + s) * 512 + hh * 64 + j] = 0.5f * (lv + acc);
    }
  }
}

// ---------------------------------------------------------------------------
// Wo gemm + bias + residual(h) -> d_out (pre-layernorm)
// ---------------------------------------------------------------------------
__global__ __launch_bounds__(256) void gemm_wo(
    const float* __restrict__ A, const float* __restrict__ Bm,
    const float* __restrict__ bo, const float* __restrict__ h,
    float* __restrict__ outp) {
  int m0 = blockIdx.x * 64;
  int n0 = blockIdx.y * 64;
  int tid = threadIdx.x;
  __shared__ float As[16][68];
  __shared__ float Bs[16][68];
  int tm = tid >> 4, tn = tid & 15;
  int ra = tid >> 2, ca = (tid & 3) * 4;
  int rb = tid >> 4, cb = (tid & 15) * 4;
  float acc[4][4] = {};
  for (int k0 = 0; k0 < 512; k0 += 16) {
    float4 av = *(const float4*)(A + (m0 + ra) * 512 + k0 + ca);
    float4 bv = *(const float4*)(Bm + (k0 + rb) * 512 + n0 + cb);
    As[ca + 0][ra] = av.x; As[ca + 1][ra] = av.y;
    As[ca + 2][ra] = av.z; As[ca + 3][ra] = av.w;
    *(float4*)&Bs[rb][cb] = bv;
    __syncthreads();
#pragma unroll
    for (int k = 0; k < 16; k++) {
      float4 a4 = *(const float4*)&As[k][tm * 4];
      float4 b4 = *(const float4*)&Bs[k][tn * 4];
      float av_[4] = {a4.x, a4.y, a4.z, a4.w};
      float bv_[4] = {b4.x, b4.y, b4.z, b4.w};
#pragma unroll
      for (int i = 0; i < 4; i++)
#pragma unroll
        for (int j = 0; j < 4; j++) acc[i][j] += av_[i] * bv_[j];
    }
    __syncthreads();
  }
  float bjs[4];
#pragma unroll
  for (int j = 0; j < 4; j++) bjs[j] = bo[n0 + tn * 4 + j];
#pragma unroll
  for (int i = 0; i < 4; i++) {
    int m = m0 + tm * 4 + i;
    const float* hp = h + m * 512 + n0 + tn * 4;
    float4 h4 = *(const float4*)hp;
    float4 o4 = make_float4(acc[i][0] + bjs[0] + h4.x,
                            acc[i][1] + bjs[1] + h4.y,
                            acc[i][2] + bjs[2] + h4.z,
                            acc[i][3] + bjs[3] + h4.w);
    *(float4*)(outp + m * 512 + n0 + tn * 4) = o4;
  }
}

// ---------------------------------------------------------------------------
// layernorm in place on d_out, one block per row
// ---------------------------------------------------------------------------
__global__ __launch_bounds__(256) void ln_kernel(float* __restrict__ o,
                                                 const float* __restrict__ g,
                                                 const float* __restrict__ bb) {
  int row = blockIdx.x;
  int tid = threadIdx.x;
  float v0 = o[row * 512 + tid];
  float v1 = o[row * 512 + 256 + tid];
  float s = v0 + v1;
  float s2 = v0 * v0 + v1 * v1;
#pragma unroll
  for (int off = 1; off < 64; off <<= 1) {
    s += __shfl_xor(s, off);
    s2 += __shfl_xor(s2, off);
  }
  __shared__ float ps[4], ps2[4];
  int w = tid >> 6;
  if ((tid & 63) == 0) { ps[w] = s; ps2[w] = s2; }
  __syncthreads();
  float S = ps[0] + ps[1] + ps[2] + ps[3];
  float S2 = ps2[0] + ps2[1] + ps2[2] + ps2[3];
  float mu = S * (1.f / 512.f);
  float var = S2 * (1.f / 512.f) - mu * mu;
  float inv = rsqrtf(var + 1e-5f);
  o[row * 512 + tid] = (v0 - mu) * inv * g[tid] + bb[tid];
  o[row * 512 + 256 + tid] = (v1 - mu) * inv * g[tid + 256] + bb[tid + 256];
}

// ---------------------------------------------------------------------------
extern "C" void kernel_launch(void* const* d_in, const int* in_sizes, int n_in,
                              void* d_out, int out_size, void* d_ws,
                              size_t ws_size, hipStream_t stream) {
  const float* x   = (const float*)d_in[0];
  const float* w1  = (const float*)d_in[1];
  const float* b1  = (const float*)d_in[2];
  const float* w2  = (const float*)d_in[3];
  const float* b2  = (const float*)d_in[4];
  const float* w3  = (const float*)d_in[5];
  const float* b3  = (const float*)d_in[6];
  const float* Wq  = (const float*)d_in[7];
  const float* bq  = (const float*)d_in[8];
  const float* Wk  = (const float*)d_in[9];
  const float* bk  = (const float*)d_in[10];
  const float* Wv  = (const float*)d_in[11];
  const float* bv  = (const float*)d_in[12];
  const float* Wkp = (const float*)d_in[13];
  const float* bkp = (const float*)d_in[14];
  const float* Wvp = (const float*)d_in[15];
  const float* bvp = (const float*)d_in[16];
  const float* Wo  = (const float*)d_in[17];
  const float* bo  = (const float*)d_in[18];
  const float* lng = (const float*)d_in[19];
  const float* lnb = (const float*)d_in[20];

  float* ws    = (float*)d_ws;
  float* WallT = ws;                     // 786432
  float* ball  = WallT + 786432;         // 1536
  float* WoT   = ball + 1536;            // 262144
  float* h     = WoT + 262144;           // 2097152 each below
  float* Qb    = h + 2097152;
  float* Kb    = Qb + 2097152;
  float* Vb    = Kb + 2097152;
  float* KpT   = Vb + 2097152;
  float* Vpb   = KpT + 2097152;
  float* ctxl  = Vpb + 2097152;
  float* ctxc  = ctxl + 2097152;
  float* outF  = (float*)d_out;

  prep_kernel<<<512, 256, 0, stream>>>(Wq, Wk, Wv, bq, bk, bv, Wo, WallT, ball,
                                       WoT);
  conv_kernel<<<512, 256, 0, stream>>>(x, w1, b1, w2, b2, w3, b3, h);
  {
    dim3 g(64, 24);
    gemm_qkv<<<g, 256, 0, stream>>>(h, WallT, ball, Qb, Kb, Vb);
  }
  kpvp_kernel<<<256, 256, 0, stream>>>(Kb, Vb, Wkp, bkp, Wvp, bvp, KpT, Vpb);
  local_attn<<<8192, 256, 0, stream>>>(Qb, Kb, Vb, ctxl);
  global_attn<<<1024, 256, 0, stream>>>(Qb, KpT, Vpb, Wvp, bvp, ctxl, ctxc);
  {
    dim3 g(64, 8);
    gemm_wo<<<g, 256, 0, stream>>>(ctxc, WoT, bo, h, outF);
  }
  ln_kernel<<<4096, 256, 0, stream>>>(outF, lng, lnb);
}

// Round 3
// 819.615 us; speedup vs baseline: 1.7982x; 1.1674x over previous
//
#include <hip/hip_runtime.h>
#include <hip/hip_bf16.h>

#define BB 2
#define SS 2048
#define INC 64
#define HIDN 512
#define NHH 8
#define HDD 64

typedef __attribute__((ext_vector_type(8))) short bf16x8;
typedef __attribute__((ext_vector_type(4))) float f32x4;

__device__ __forceinline__ short f2bf(float f) {
  union { __hip_bfloat16 h; short s; } u;
  u.h = __float2bfloat16(f);
  return u.s;
}
__device__ __forceinline__ int pack2bf(float lo, float hi) {
  return (int)((unsigned short)f2bf(lo) | ((unsigned)(unsigned short)f2bf(hi) << 16));
}

// ---------------------------------------------------------------------------
// prep: transpose Wq/Wk/Wv into WallT (512 x 1536), Wo into WoT (512x512),
// concat biases into ball (1536)
// ---------------------------------------------------------------------------
__global__ __launch_bounds__(256) void prep_kernel(
    const float* __restrict__ Wq, const float* __restrict__ Wk_,
    const float* __restrict__ Wv_, const float* __restrict__ bq,
    const float* __restrict__ bk_, const float* __restrict__ bv_,
    const float* __restrict__ Wo, float* __restrict__ WallT,
    float* __restrict__ ball, float* __restrict__ WoT) {
  int i0 = blockIdx.x * 256 + threadIdx.x;
  int stride = gridDim.x * 256;
  for (int idx = i0; idx < 512 * 1536; idx += stride) {
    int k = idx / 1536, n = idx % 1536;
    float v;
    if (n < 512)       v = Wq[n * 512 + k];
    else if (n < 1024) v = Wk_[(n - 512) * 512 + k];
    else               v = Wv_[(n - 1024) * 512 + k];
    WallT[idx] = v;
  }
  for (int idx = i0; idx < 512 * 512; idx += stride) {
    WoT[idx] = Wo[(idx % 512) * 512 + (idx / 512)];
  }
  if (i0 < 1536) {
    float v;
    if (i0 < 512)       v = bq[i0];
    else if (i0 < 1024) v = bk_[i0 - 512];
    else                v = bv_[i0 - 1024];
    ball[i0] = v;
  }
}

// ---------------------------------------------------------------------------
// conv: h[b,s,c] = relu(conv{1,2,3}(x)) concat over channels. 8 s per block.
// ---------------------------------------------------------------------------
template <int KW, int OFF>
__device__ __forceinline__ void conv_channel(const float* __restrict__ w,
                                             const float* xs, float bias,
                                             float acc[8]) {
#pragma unroll
  for (int i = 0; i < 8; i++) acc[i] = bias;
  for (int ci = 0; ci < 64; ci++) {
    float xv[8 + KW - 1];
#pragma unroll
    for (int r = 0; r < 8 + KW - 1; r++) xv[r] = xs[(r + OFF) * 64 + ci];
#pragma unroll
    for (int k = 0; k < KW; k++) {
      float wv = w[ci * KW + k];
#pragma unroll
      for (int i = 0; i < 8; i++) acc[i] += xv[i + k] * wv;
    }
  }
}

__global__ __launch_bounds__(256) void conv_kernel(
    const float* __restrict__ x, const float* __restrict__ w1,
    const float* __restrict__ b1, const float* __restrict__ w2,
    const float* __restrict__ b2, const float* __restrict__ w3,
    const float* __restrict__ b3, float* __restrict__ h) {
  const int TS = 8;
  int blk = blockIdx.x;                 // 512 blocks
  int b = blk / (SS / TS);
  int s0 = (blk % (SS / TS)) * TS;
  __shared__ float xs[(TS + 6) * 64];   // rows s0-3 .. s0+TS+2
  int tid = threadIdx.x;
  for (int i = tid; i < (TS + 6) * 64; i += 256) {
    int row = i >> 6, ci = i & 63;
    int sgl = s0 + row - 3;
    xs[i] = (sgl >= 0 && sgl < SS) ? x[(b * SS + sgl) * 64 + ci] : 0.f;
  }
  __syncthreads();
  for (int c = tid; c < 512; c += 256) {
    float acc[8];
    if (c < 171) {
      conv_channel<3, 2>(w1 + c * (64 * 3), xs, b1[c], acc);
    } else if (c < 342) {
      conv_channel<5, 1>(w2 + (c - 171) * (64 * 5), xs, b2[c - 171], acc);
    } else {
      conv_channel<7, 0>(w3 + (c - 342) * (64 * 7), xs, b3[c - 342], acc);
    }
#pragma unroll
    for (int i = 0; i < 8; i++)
      h[(b * SS + s0 + i) * 512 + c] = fmaxf(acc[i], 0.f);
  }
}

// ---------------------------------------------------------------------------
// QKV gemm: C(4096 x 1536) = h(4096x512) @ WallT(512x1536) + ball,
// scattered into Q/K/V (B,NH,S,HD); also emits bf16 copy of Q (Qh).
// ---------------------------------------------------------------------------
__global__ __launch_bounds__(256) void gemm_qkv(
    const float* __restrict__ A, const float* __restrict__ Bm,
    const float* __restrict__ bias, float* __restrict__ Qo,
    float* __restrict__ Ko, float* __restrict__ Vo,
    short* __restrict__ Qh) {
  int m0 = blockIdx.x * 64;
  int n0 = blockIdx.y * 64;
  int tid = threadIdx.x;
  __shared__ float As[16][68];  // [k][m]
  __shared__ float Bs[16][68];  // [k][n]
  int tm = tid >> 4, tn = tid & 15;
  int ra = tid >> 2, ca = (tid & 3) * 4;
  int rb = tid >> 4, cb = (tid & 15) * 4;
  float acc[4][4] = {};
  for (int k0 = 0; k0 < 512; k0 += 16) {
    float4 av = *(const float4*)(A + (m0 + ra) * 512 + k0 + ca);
    float4 bv = *(const float4*)(Bm + (k0 + rb) * 1536 + n0 + cb);
    As[ca + 0][ra] = av.x; As[ca + 1][ra] = av.y;
    As[ca + 2][ra] = av.z; As[ca + 3][ra] = av.w;
    *(float4*)&Bs[rb][cb] = bv;
    __syncthreads();
#pragma unroll
    for (int k = 0; k < 16; k++) {
      float4 a4 = *(const float4*)&As[k][tm * 4];
      float4 b4 = *(const float4*)&Bs[k][tn * 4];
      float av_[4] = {a4.x, a4.y, a4.z, a4.w};
      float bv_[4] = {b4.x, b4.y, b4.z, b4.w};
#pragma unroll
      for (int i = 0; i < 4; i++)
#pragma unroll
        for (int j = 0; j < 4; j++) acc[i][j] += av_[i] * bv_[j];
    }
    __syncthreads();
  }
  int which = n0 >> 9;
  int head = (n0 >> 6) & 7;
  float* dst = which == 0 ? Qo : (which == 1 ? Ko : Vo);
  float bjs[4];
#pragma unroll
  for (int j = 0; j < 4; j++) bjs[j] = bias[n0 + tn * 4 + j];
#pragma unroll
  for (int i = 0; i < 4; i++) {
    int m = m0 + tm * 4 + i;
    int bb = m >> 11, s = m & 2047;
    float* dp = dst + ((bb * 8 + head) * 2048 + s) * 64 + tn * 4;
    float4 o4 = make_float4(acc[i][0] + bjs[0], acc[i][1] + bjs[1],
                            acc[i][2] + bjs[2], acc[i][3] + bjs[3]);
    *(float4*)dp = o4;
    if (which == 0) {
      short4 q4s;
      q4s.x = f2bf(o4.x); q4s.y = f2bf(o4.y);
      q4s.z = f2bf(o4.z); q4s.w = f2bf(o4.w);
      *(short4*)(Qh + (dp - Qo)) = q4s;
    }
  }
}

// ---------------------------------------------------------------------------
// Kp (bf16 rows, B,NH,S,R) and Vp (fp32, B,NH,S,R) projections
// ---------------------------------------------------------------------------
__global__ __launch_bounds__(256) void kpvp_kernel(
    const float* __restrict__ K, const float* __restrict__ V,
    const float* __restrict__ Wkp, const float* __restrict__ bkp,
    const float* __restrict__ Wvp, const float* __restrict__ bvp,
    short* __restrict__ Kph, float* __restrict__ Vp) {
  int bh = blockIdx.x >> 4;            // 256 blocks: B*NH * (S/128)
  int k0 = (blockIdx.x & 15) * 128;
  int tid = threadIdx.x;
  __shared__ float tile[128][65];
  __shared__ float Wb[64][65];
  // ---- phase 1: Kph (bf16 row-major [key][64]) ----
  for (int i = tid; i < 128 * 64; i += 256)
    tile[i >> 6][i & 63] = K[(bh * 2048 + k0 + (i >> 6)) * 64 + (i & 63)];
  for (int i = tid; i < 4096; i += 256) Wb[i >> 6][i & 63] = Wkp[i];
  __syncthreads();
  {
    int kl = tid & 63, rbase = (tid >> 6) * 16;
    for (int half = 0; half < 2; half++) {
      int kk = kl + half * 64;
      int packed[8];
#pragma unroll
      for (int ri = 0; ri < 16; ri += 2) {
        float a0 = bkp[rbase + ri], a1 = bkp[rbase + ri + 1];
#pragma unroll 8
        for (int d = 0; d < 64; d++) {
          float t = tile[kk][d];
          a0 += t * Wb[rbase + ri][d];
          a1 += t * Wb[rbase + ri + 1][d];
        }
        packed[ri >> 1] = pack2bf(a0, a1);
      }
      int4* dst = (int4*)(Kph + (size_t)(bh * 2048 + k0 + kk) * 64 + rbase);
      dst[0] = make_int4(packed[0], packed[1], packed[2], packed[3]);
      dst[1] = make_int4(packed[4], packed[5], packed[6], packed[7]);
    }
  }
  __syncthreads();
  // ---- phase 2: Vp ----
  for (int i = tid; i < 128 * 64; i += 256)
    tile[i >> 6][i & 63] = V[(bh * 2048 + k0 + (i >> 6)) * 64 + (i & 63)];
  for (int i = tid; i < 4096; i += 256) Wb[i >> 6][i & 63] = Wvp[i];
  __syncthreads();
  {
    int r = tid & 63, kb = tid >> 6;
    for (int ri = 0; ri < 32; ri++) {
      int kk = kb + ri * 4;
      float acc = bvp[r];
#pragma unroll 8
      for (int d = 0; d < 64; d++) acc += tile[kk][d] * Wb[r][d];
      Vp[(bh * 2048 + k0 + kk) * 64 + r] = acc;
    }
  }
}

// ---------------------------------------------------------------------------
// local windowed attention: one wave per query
// ---------------------------------------------------------------------------
__global__ __launch_bounds__(256) void local_attn(
    const float* __restrict__ Q, const float* __restrict__ K,
    const float* __restrict__ V, float* __restrict__ ctxl) {
  int idx = blockIdx.x * 4 + (threadIdx.x >> 6);  // global query over B*NH*S
  int lane = threadIdx.x & 63;
  int bh = idx >> 11;
  int s = idx & 2047;
  float qd = Q[idx * 64 + lane];
  float sc[5];
  bool ok[5];
#pragma unroll
  for (int j = 0; j < 5; j++) {
    int sj = s + j - 2;
    ok[j] = (sj >= 0 && sj < SS);
    float p = ok[j] ? qd * K[(bh * 2048 + sj) * 64 + lane] : 0.f;
    p += __shfl_xor(p, 1);  p += __shfl_xor(p, 2);  p += __shfl_xor(p, 4);
    p += __shfl_xor(p, 8);  p += __shfl_xor(p, 16); p += __shfl_xor(p, 32);
    sc[j] = p * 0.125f;
  }
  float m = -3.0e38f;
#pragma unroll
  for (int j = 0; j < 5; j++)
    if (ok[j]) m = fmaxf(m, sc[j]);
  float e[5], l = 0.f;
#pragma unroll
  for (int j = 0; j < 5; j++) {
    e[j] = ok[j] ? expf(sc[j] - m) : 0.f;
    l += e[j];
  }
  float inv = 1.f / l;
  float o = 0.f;
#pragma unroll
  for (int j = 0; j < 5; j++) {
    int sj = s + j - 2;
    if (ok[j]) o += e[j] * inv * V[(bh * 2048 + sj) * 64 + lane];
  }
  ctxl[idx * 64 + lane] = o;
}

// ---------------------------------------------------------------------------
// global sparse attention, MFMA edition. One wave = 16 queries x all keys.
// No __syncthreads at all; wave-synchronous LDS only.
// D[row][col]: row(query) = (lane>>4)*4 + reg, col(key) = lane&15.
// A/B fragments: elem j at k = (lane>>4)*8 + j, row = lane&15 (contig 16B).
// ---------------------------------------------------------------------------
__global__ __launch_bounds__(64) void global_attn(
    const short* __restrict__ Qh, const short* __restrict__ Kph,
    const float* __restrict__ Vp, const float* __restrict__ Wvp,
    const float* __restrict__ bvp, const float* __restrict__ ctxl,
    float* __restrict__ ctxc) {
  int wid = blockIdx.x;                // 2048 = 16 bh * 128 q-tiles
  int bh = wid >> 7;
  int q0 = (wid & 127) * 16;
  int b = bh >> 3, hh = bh & 7;
  int lane = threadIdx.x;
  int quad = lane >> 4;
  int l16 = lane & 15;

  __shared__ float topv[16][17];
  __shared__ int   topi[16][17];
  __shared__ float sbuf[16][17];
  __shared__ float tw[16][16];
  __shared__ float spr[16][68];

  for (int i = lane; i < 16 * 17; i += 64) {
    topv[i / 17][i % 17] = -3.0e38f;
    topi[i / 17][i % 17] = 0;
  }
  __builtin_amdgcn_wave_barrier();

  const short* qbase = Qh + (size_t)(bh * 2048 + q0 + l16) * 64 + quad * 8;
  bf16x8 a0 = *(const bf16x8*)qbase;
  bf16x8 a1 = *(const bf16x8*)(qbase + 32);

  const short* kbase = Kph + (size_t)(bh * 2048 + l16) * 64 + quad * 8;
  bf16x8 b0 = *(const bf16x8*)kbase;
  bf16x8 b1 = *(const bf16x8*)(kbase + 32);

  float rvmin0 = -3.0e38f, rvmin1 = -3.0e38f;
  float rvmin2 = -3.0e38f, rvmin3 = -3.0e38f;

  for (int g = 0; g < 128; g++) {
    int gn = (g + 1 < 128) ? g + 1 : 127;
    bf16x8 nb0 = *(const bf16x8*)(kbase + gn * 1024);
    bf16x8 nb1 = *(const bf16x8*)(kbase + gn * 1024 + 32);
    f32x4 C = {0.f, 0.f, 0.f, 0.f};
    C = __builtin_amdgcn_mfma_f32_16x16x32_bf16(a0, b0, C, 0, 0, 0);
    C = __builtin_amdgcn_mfma_f32_16x16x32_bf16(a1, b1, C, 0, 0, 0);
    float s0 = C[0] * 0.125f, s1 = C[1] * 0.125f;
    float s2 = C[2] * 0.125f, s3 = C[3] * 0.125f;
    bool pred = (s0 > rvmin0) | (s1 > rvmin1) | (s2 > rvmin2) | (s3 > rvmin3);
    if (__ballot(pred)) {
      int qb = quad * 4;
      sbuf[qb + 0][l16] = s0;
      sbuf[qb + 1][l16] = s1;
      sbuf[qb + 2][l16] = s2;
      sbuf[qb + 3][l16] = s3;
      __builtin_amdgcn_wave_barrier();
      if (lane < 16) {
        float vmin = topv[lane][15];
        int kg = g * 16;
#pragma unroll 1
        for (int kk = 0; kk < 16; kk++) {
          float v = sbuf[lane][kk];
          if (v > vmin) {
            int p = 15;
            while (p > 0 && topv[lane][p - 1] < v) {
              topv[lane][p] = topv[lane][p - 1];
              topi[lane][p] = topi[lane][p - 1];
              p--;
            }
            topv[lane][p] = v;
            topi[lane][p] = kg + kk;
            vmin = topv[lane][15];
          }
        }
      }
      __builtin_amdgcn_wave_barrier();
      rvmin0 = topv[quad * 4 + 0][15];
      rvmin1 = topv[quad * 4 + 1][15];
      rvmin2 = topv[quad * 4 + 2][15];
      rvmin3 = topv[quad * 4 + 3][15];
    }
    b0 = nb0;
    b1 = nb1;
  }

  // softmax over the 16 kept scores (sorted desc; topv[q][0] is max)
  if (lane < 16) {
    float m = topv[lane][0];
    float ev[16], l = 0.f;
#pragma unroll
    for (int j = 0; j < 16; j++) {
      ev[j] = expf(topv[lane][j] - m);
      l += ev[j];
    }
    float inv = 1.f / l;
#pragma unroll
    for (int j = 0; j < 16; j++) tw[lane][j] = ev[j] * inv;
  }
  __builtin_amdgcn_wave_barrier();

  // gather: 4 lanes per query, 16 r each -> spr[q][64]
  {
    int q = lane >> 2, rl = (lane & 3) * 16;
    float accr[16] = {};
#pragma unroll 4
    for (int j = 0; j < 16; j++) {
      float w = tw[q][j];
      const float* vrow = Vp + (size_t)(bh * 2048 + topi[q][j]) * 64 + rl;
      float4 v0 = *(const float4*)(vrow + 0);
      float4 v1 = *(const float4*)(vrow + 4);
      float4 v2 = *(const float4*)(vrow + 8);
      float4 v3 = *(const float4*)(vrow + 12);
      accr[0] += w * v0.x;  accr[1] += w * v0.y;
      accr[2] += w * v0.z;  accr[3] += w * v0.w;
      accr[4] += w * v1.x;  accr[5] += w * v1.y;
      accr[6] += w * v1.z;  accr[7] += w * v1.w;
      accr[8] += w * v2.x;  accr[9] += w * v2.y;
      accr[10] += w * v2.z; accr[11] += w * v2.w;
      accr[12] += w * v3.x; accr[13] += w * v3.y;
      accr[14] += w * v3.z; accr[15] += w * v3.w;
    }
#pragma unroll
    for (int u = 0; u < 16; u += 4)
      *(float4*)&spr[q][rl + u] =
          make_float4(accr[u], accr[u + 1], accr[u + 2], accr[u + 3]);
  }
  __builtin_amdgcn_wave_barrier();

  // projection sp @ Wvp^T + bvp, combine with local, write ctxc
  {
    int q = lane >> 2, jb = (lane & 3) * 16;
    float accj[16];
#pragma unroll
    for (int u = 0; u < 16; u++) accj[u] = bvp[jb + u];
    for (int r = 0; r < 64; r += 4) {
      float4 sp4 = *(const float4*)&spr[q][r];
#pragma unroll
      for (int u = 0; u < 16; u++) {
        float4 w4 = *(const float4*)(Wvp + (jb + u) * 64 + r);
        accj[u] += sp4.x * w4.x + sp4.y * w4.y + sp4.z * w4.z + sp4.w * w4.w;
      }
    }
    int s = q0 + q;
    const float* lrow = ctxl + (size_t)(bh * 2048 + s) * 64 + jb;
    float* orow = ctxc + (size_t)(b * 2048 + s) * 512 + hh * 64 + jb;
#pragma unroll
    for (int u = 0; u < 16; u += 4) {
      float4 lv = *(const float4*)(lrow + u);
      *(float4*)(orow + u) =
          make_float4(0.5f * (lv.x + accj[u]), 0.5f * (lv.y + accj[u + 1]),
                      0.5f * (lv.z + accj[u + 2]), 0.5f * (lv.w + accj[u + 3]));
    }
  }
}

// ---------------------------------------------------------------------------
// Wo gemm + bias + residual(h) -> d_out (pre-layernorm)
// ---------------------------------------------------------------------------
__global__ __launch_bounds__(256) void gemm_wo(
    const float* __restrict__ A, const float* __restrict__ Bm,
    const float* __restrict__ bo, const float* __restrict__ h,
    float* __restrict__ outp) {
  int m0 = blockIdx.x * 64;
  int n0 = blockIdx.y * 64;
  int tid = threadIdx.x;
  __shared__ float As[16][68];
  __shared__ float Bs[16][68];
  int tm = tid >> 4, tn = tid & 15;
  int ra = tid >> 2, ca = (tid & 3) * 4;
  int rb = tid >> 4, cb = (tid & 15) * 4;
  float acc[4][4] = {};
  for (int k0 = 0; k0 < 512; k0 += 16) {
    float4 av = *(const float4*)(A + (m0 + ra) * 512 + k0 + ca);
    float4 bv = *(const float4*)(Bm + (k0 + rb) * 512 + n0 + cb);
    As[ca + 0][ra] = av.x; As[ca + 1][ra] = av.y;
    As[ca + 2][ra] = av.z; As[ca + 3][ra] = av.w;
    *(float4*)&Bs[rb][cb] = bv;
    __syncthreads();
#pragma unroll
    for (int k = 0; k < 16; k++) {
      float4 a4 = *(const float4*)&As[k][tm * 4];
      float4 b4 = *(const float4*)&Bs[k][tn * 4];
      float av_[4] = {a4.x, a4.y, a4.z, a4.w};
      float bv_[4] = {b4.x, b4.y, b4.z, b4.w};
#pragma unroll
      for (int i = 0; i < 4; i++)
#pragma unroll
        for (int j = 0; j < 4; j++) acc[i][j] += av_[i] * bv_[j];
    }
    __syncthreads();
  }
  float bjs[4];
#pragma unroll
  for (int j = 0; j < 4; j++) bjs[j] = bo[n0 + tn * 4 + j];
#pragma unroll
  for (int i = 0; i < 4; i++) {
    int m = m0 + tm * 4 + i;
    const float* hp = h + m * 512 + n0 + tn * 4;
    float4 h4 = *(const float4*)hp;
    float4 o4 = make_float4(acc[i][0] + bjs[0] + h4.x,
                            acc[i][1] + bjs[1] + h4.y,
                            acc[i][2] + bjs[2] + h4.z,
                            acc[i][3] + bjs[3] + h4.w);
    *(float4*)(outp + m * 512 + n0 + tn * 4) = o4;
  }
}

// ---------------------------------------------------------------------------
// layernorm in place on d_out, one block per row
// ---------------------------------------------------------------------------
__global__ __launch_bounds__(256) void ln_kernel(float* __restrict__ o,
                                                 const float* __restrict__ g,
                                                 const float* __restrict__ bb) {
  int row = blockIdx.x;
  int tid = threadIdx.x;
  float v0 = o[row * 512 + tid];
  float v1 = o[row * 512 + 256 + tid];
  float s = v0 + v1;
  float s2 = v0 * v0 + v1 * v1;
#pragma unroll
  for (int off = 1; off < 64; off <<= 1) {
    s += __shfl_xor(s, off);
    s2 += __shfl_xor(s2, off);
  }
  __shared__ float ps[4], ps2[4];
  int w = tid >> 6;
  if ((tid & 63) == 0) { ps[w] = s; ps2[w] = s2; }
  __syncthreads();
  float S = ps[0] + ps[1] + ps[2] + ps[3];
  float S2 = ps2[0] + ps2[1] + ps2[2] + ps2[3];
  float mu = S * (1.f / 512.f);
  float var = S2 * (1.f / 512.f) - mu * mu;
  float inv = rsqrtf(var + 1e-5f);
  o[row * 512 + tid] = (v0 - mu) * inv * g[tid] + bb[tid];
  o[row * 512 + 256 + tid] = (v1 - mu) * inv * g[tid + 256] + bb[tid + 256];
}

// ---------------------------------------------------------------------------
extern "C" void kernel_launch(void* const* d_in, const int* in_sizes, int n_in,
                              void* d_out, int out_size, void* d_ws,
                              size_t ws_size, hipStream_t stream) {
  const float* x   = (const float*)d_in[0];
  const float* w1  = (const float*)d_in[1];
  const float* b1  = (const float*)d_in[2];
  const float* w2  = (const float*)d_in[3];
  const float* b2  = (const float*)d_in[4];
  const float* w3  = (const float*)d_in[5];
  const float* b3  = (const float*)d_in[6];
  const float* Wq  = (const float*)d_in[7];
  const float* bq  = (const float*)d_in[8];
  const float* Wk  = (const float*)d_in[9];
  const float* bk  = (const float*)d_in[10];
  const float* Wv  = (const float*)d_in[11];
  const float* bv  = (const float*)d_in[12];
  const float* Wkp = (const float*)d_in[13];
  const float* bkp = (const float*)d_in[14];
  const float* Wvp = (const float*)d_in[15];
  const float* bvp = (const float*)d_in[16];
  const float* Wo  = (const float*)d_in[17];
  const float* bo  = (const float*)d_in[18];
  const float* lng = (const float*)d_in[19];
  const float* lnb = (const float*)d_in[20];

  float* ws    = (float*)d_ws;
  float* WallT = ws;                     // 786432
  float* ball  = WallT + 786432;         // 1536
  float* WoT   = ball + 1536;            // 262144
  float* h     = WoT + 262144;           // 2097152 floats each below
  float* Qb    = h + 2097152;
  float* Kb    = Qb + 2097152;
  float* Vb    = Kb + 2097152;
  float* bf16slot = Vb + 2097152;        // 8 MB: Kph (4MB) + Qh (4MB)
  float* Vpb   = bf16slot + 2097152;
  float* ctxl  = Vpb + 2097152;
  float* ctxc  = ctxl + 2097152;
  float* outF  = (float*)d_out;

  short* Kph = (short*)bf16slot;
  short* Qh  = Kph + 2097152;

  prep_kernel<<<512, 256, 0, stream>>>(Wq, Wk, Wv, bq, bk, bv, Wo, WallT, ball,
                                       WoT);
  conv_kernel<<<512, 256, 0, stream>>>(x, w1, b1, w2, b2, w3, b3, h);
  {
    dim3 g(64, 24);
    gemm_qkv<<<g, 256, 0, stream>>>(h, WallT, ball, Qb, Kb, Vb, Qh);
  }
  kpvp_kernel<<<256, 256, 0, stream>>>(Kb, Vb, Wkp, bkp, Wvp, bvp, Kph, Vpb);
  local_attn<<<8192, 256, 0, stream>>>(Qb, Kb, Vb, ctxl);
  global_attn<<<2048, 64, 0, stream>>>(Qh, Kph, Vpb, Wvp, bvp, ctxl, ctxc);
  {
    dim3 g(64, 8);
    gemm_wo<<<g, 256, 0, stream>>>(ctxc, WoT, bo, h, outF);
  }
  ln_kernel<<<4096, 256, 0, stream>>>(outF, lng, lnb);
}

// Round 4
// 555.299 us; speedup vs baseline: 2.6541x; 1.4760x over previous
//
#include <hip/hip_runtime.h>
#include <hip/hip_bf16.h>

#define BB 2
#define SS 2048
#define INC 64
#define HIDN 512
#define NHH 8
#define HDD 64

typedef __attribute__((ext_vector_type(8))) short bf16x8;
typedef __attribute__((ext_vector_type(4))) float f32x4;

__device__ __forceinline__ short f2bf(float f) {
  union { __hip_bfloat16 h; short s; } u;
  u.h = __float2bfloat16(f);
  return u.s;
}
__device__ __forceinline__ int pack2bf(float lo, float hi) {
  return (int)((unsigned short)f2bf(lo) | ((unsigned)(unsigned short)f2bf(hi) << 16));
}

// ---------------------------------------------------------------------------
// prep: transpose Wq/Wk/Wv into WallT (512 x 1536), Wo into WoT (512x512),
// concat biases into ball (1536)
// ---------------------------------------------------------------------------
__global__ __launch_bounds__(256) void prep_kernel(
    const float* __restrict__ Wq, const float* __restrict__ Wk_,
    const float* __restrict__ Wv_, const float* __restrict__ bq,
    const float* __restrict__ bk_, const float* __restrict__ bv_,
    const float* __restrict__ Wo, float* __restrict__ WallT,
    float* __restrict__ ball, float* __restrict__ WoT) {
  int i0 = blockIdx.x * 256 + threadIdx.x;
  int stride = gridDim.x * 256;
  for (int idx = i0; idx < 512 * 1536; idx += stride) {
    int k = idx / 1536, n = idx % 1536;
    float v;
    if (n < 512)       v = Wq[n * 512 + k];
    else if (n < 1024) v = Wk_[(n - 512) * 512 + k];
    else               v = Wv_[(n - 1024) * 512 + k];
    WallT[idx] = v;
  }
  for (int idx = i0; idx < 512 * 512; idx += stride) {
    WoT[idx] = Wo[(idx % 512) * 512 + (idx / 512)];
  }
  if (i0 < 1536) {
    float v;
    if (i0 < 512)       v = bq[i0];
    else if (i0 < 1024) v = bk_[i0 - 512];
    else                v = bv_[i0 - 1024];
    ball[i0] = v;
  }
}

// ---------------------------------------------------------------------------
// conv: h[b,s,c] = relu(conv{1,2,3}(x)) concat over channels. 8 s per block.
// ---------------------------------------------------------------------------
template <int KW, int OFF>
__device__ __forceinline__ void conv_channel(const float* __restrict__ w,
                                             const float* xs, float bias,
                                             float acc[8]) {
#pragma unroll
  for (int i = 0; i < 8; i++) acc[i] = bias;
  for (int ci = 0; ci < 64; ci++) {
    float xv[8 + KW - 1];
#pragma unroll
    for (int r = 0; r < 8 + KW - 1; r++) xv[r] = xs[(r + OFF) * 64 + ci];
#pragma unroll
    for (int k = 0; k < KW; k++) {
      float wv = w[ci * KW + k];
#pragma unroll
      for (int i = 0; i < 8; i++) acc[i] += xv[i + k] * wv;
    }
  }
}

__global__ __launch_bounds__(256) void conv_kernel(
    const float* __restrict__ x, const float* __restrict__ w1,
    const float* __restrict__ b1, const float* __restrict__ w2,
    const float* __restrict__ b2, const float* __restrict__ w3,
    const float* __restrict__ b3, float* __restrict__ h) {
  const int TS = 8;
  int blk = blockIdx.x;                 // 512 blocks
  int b = blk / (SS / TS);
  int s0 = (blk % (SS / TS)) * TS;
  __shared__ float xs[(TS + 6) * 64];   // rows s0-3 .. s0+TS+2
  int tid = threadIdx.x;
  for (int i = tid; i < (TS + 6) * 64; i += 256) {
    int row = i >> 6, ci = i & 63;
    int sgl = s0 + row - 3;
    xs[i] = (sgl >= 0 && sgl < SS) ? x[(b * SS + sgl) * 64 + ci] : 0.f;
  }
  __syncthreads();
  for (int c = tid; c < 512; c += 256) {
    float acc[8];
    if (c < 171) {
      conv_channel<3, 2>(w1 + c * (64 * 3), xs, b1[c], acc);
    } else if (c < 342) {
      conv_channel<5, 1>(w2 + (c - 171) * (64 * 5), xs, b2[c - 171], acc);
    } else {
      conv_channel<7, 0>(w3 + (c - 342) * (64 * 7), xs, b3[c - 342], acc);
    }
#pragma unroll
    for (int i = 0; i < 8; i++)
      h[(b * SS + s0 + i) * 512 + c] = fmaxf(acc[i], 0.f);
  }
}

// ---------------------------------------------------------------------------
// QKV gemm: C(4096 x 1536) = h(4096x512) @ WallT(512x1536) + ball,
// scattered into Q/K/V (B,NH,S,HD); also emits bf16 copy of Q (Qh).
// ---------------------------------------------------------------------------
__global__ __launch_bounds__(256) void gemm_qkv(
    const float* __restrict__ A, const float* __restrict__ Bm,
    const float* __restrict__ bias, float* __restrict__ Qo,
    float* __restrict__ Ko, float* __restrict__ Vo,
    short* __restrict__ Qh) {
  int m0 = blockIdx.x * 64;
  int n0 = blockIdx.y * 64;
  int tid = threadIdx.x;
  __shared__ float As[16][68];  // [k][m]
  __shared__ float Bs[16][68];  // [k][n]
  int tm = tid >> 4, tn = tid & 15;
  int ra = tid >> 2, ca = (tid & 3) * 4;
  int rb = tid >> 4, cb = (tid & 15) * 4;
  float acc[4][4] = {};
  for (int k0 = 0; k0 < 512; k0 += 16) {
    float4 av = *(const float4*)(A + (m0 + ra) * 512 + k0 + ca);
    float4 bv = *(const float4*)(Bm + (k0 + rb) * 1536 + n0 + cb);
    As[ca + 0][ra] = av.x; As[ca + 1][ra] = av.y;
    As[ca + 2][ra] = av.z; As[ca + 3][ra] = av.w;
    *(float4*)&Bs[rb][cb] = bv;
    __syncthreads();
#pragma unroll
    for (int k = 0; k < 16; k++) {
      float4 a4 = *(const float4*)&As[k][tm * 4];
      float4 b4 = *(const float4*)&Bs[k][tn * 4];
      float av_[4] = {a4.x, a4.y, a4.z, a4.w};
      float bv_[4] = {b4.x, b4.y, b4.z, b4.w};
#pragma unroll
      for (int i = 0; i < 4; i++)
#pragma unroll
        for (int j = 0; j < 4; j++) acc[i][j] += av_[i] * bv_[j];
    }
    __syncthreads();
  }
  int which = n0 >> 9;
  int head = (n0 >> 6) & 7;
  float* dst = which == 0 ? Qo : (which == 1 ? Ko : Vo);
  float bjs[4];
#pragma unroll
  for (int j = 0; j < 4; j++) bjs[j] = bias[n0 + tn * 4 + j];
#pragma unroll
  for (int i = 0; i < 4; i++) {
    int m = m0 + tm * 4 + i;
    int bb = m >> 11, s = m & 2047;
    float* dp = dst + ((bb * 8 + head) * 2048 + s) * 64 + tn * 4;
    float4 o4 = make_float4(acc[i][0] + bjs[0], acc[i][1] + bjs[1],
                            acc[i][2] + bjs[2], acc[i][3] + bjs[3]);
    *(float4*)dp = o4;
    if (which == 0) {
      short4 q4s;
      q4s.x = f2bf(o4.x); q4s.y = f2bf(o4.y);
      q4s.z = f2bf(o4.z); q4s.w = f2bf(o4.w);
      *(short4*)(Qh + (dp - Qo)) = q4s;
    }
  }
}

// ---------------------------------------------------------------------------
// Kp (bf16 rows, B,NH,S,R) and Vp (fp32, B,NH,S,R) projections
// ---------------------------------------------------------------------------
__global__ __launch_bounds__(256) void kpvp_kernel(
    const float* __restrict__ K, const float* __restrict__ V,
    const float* __restrict__ Wkp, const float* __restrict__ bkp,
    const float* __restrict__ Wvp, const float* __restrict__ bvp,
    short* __restrict__ Kph, float* __restrict__ Vp) {
  int bh = blockIdx.x >> 4;            // 256 blocks: B*NH * (S/128)
  int k0 = (blockIdx.x & 15) * 128;
  int tid = threadIdx.x;
  __shared__ float tile[128][65];
  __shared__ float Wb[64][65];
  // ---- phase 1: Kph (bf16 row-major [key][64]) ----
  for (int i = tid; i < 128 * 64; i += 256)
    tile[i >> 6][i & 63] = K[(bh * 2048 + k0 + (i >> 6)) * 64 + (i & 63)];
  for (int i = tid; i < 4096; i += 256) Wb[i >> 6][i & 63] = Wkp[i];
  __syncthreads();
  {
    int kl = tid & 63, rbase = (tid >> 6) * 16;
    for (int half = 0; half < 2; half++) {
      int kk = kl + half * 64;
      int packed[8];
#pragma unroll
      for (int ri = 0; ri < 16; ri += 2) {
        float a0 = bkp[rbase + ri], a1 = bkp[rbase + ri + 1];
#pragma unroll 8
        for (int d = 0; d < 64; d++) {
          float t = tile[kk][d];
          a0 += t * Wb[rbase + ri][d];
          a1 += t * Wb[rbase + ri + 1][d];
        }
        packed[ri >> 1] = pack2bf(a0, a1);
      }
      int4* dst = (int4*)(Kph + (size_t)(bh * 2048 + k0 + kk) * 64 + rbase);
      dst[0] = make_int4(packed[0], packed[1], packed[2], packed[3]);
      dst[1] = make_int4(packed[4], packed[5], packed[6], packed[7]);
    }
  }
  __syncthreads();
  // ---- phase 2: Vp ----
  for (int i = tid; i < 128 * 64; i += 256)
    tile[i >> 6][i & 63] = V[(bh * 2048 + k0 + (i >> 6)) * 64 + (i & 63)];
  for (int i = tid; i < 4096; i += 256) Wb[i >> 6][i & 63] = Wvp[i];
  __syncthreads();
  {
    int r = tid & 63, kb = tid >> 6;
    for (int ri = 0; ri < 32; ri++) {
      int kk = kb + ri * 4;
      float acc = bvp[r];
#pragma unroll 8
      for (int d = 0; d < 64; d++) acc += tile[kk][d] * Wb[r][d];
      Vp[(bh * 2048 + k0 + kk) * 64 + r] = acc;
    }
  }
}

// ---------------------------------------------------------------------------
// local windowed attention: one wave per query
// ---------------------------------------------------------------------------
__global__ __launch_bounds__(256) void local_attn(
    const float* __restrict__ Q, const float* __restrict__ K,
    const float* __restrict__ V, float* __restrict__ ctxl) {
  int idx = blockIdx.x * 4 + (threadIdx.x >> 6);  // global query over B*NH*S
  int lane = threadIdx.x & 63;
  int bh = idx >> 11;
  int s = idx & 2047;
  float qd = Q[idx * 64 + lane];
  float sc[5];
  bool ok[5];
#pragma unroll
  for (int j = 0; j < 5; j++) {
    int sj = s + j - 2;
    ok[j] = (sj >= 0 && sj < SS);
    float p = ok[j] ? qd * K[(bh * 2048 + sj) * 64 + lane] : 0.f;
    p += __shfl_xor(p, 1);  p += __shfl_xor(p, 2);  p += __shfl_xor(p, 4);
    p += __shfl_xor(p, 8);  p += __shfl_xor(p, 16); p += __shfl_xor(p, 32);
    sc[j] = p * 0.125f;
  }
  float m = -3.0e38f;
#pragma unroll
  for (int j = 0; j < 5; j++)
    if (ok[j]) m = fmaxf(m, sc[j]);
  float e[5], l = 0.f;
#pragma unroll
  for (int j = 0; j < 5; j++) {
    e[j] = ok[j] ? expf(sc[j] - m) : 0.f;
    l += e[j];
  }
  float inv = 1.f / l;
  float o = 0.f;
#pragma unroll
  for (int j = 0; j < 5; j++) {
    int sj = s + j - 2;
    if (ok[j]) o += e[j] * inv * V[(bh * 2048 + sj) * 64 + lane];
  }
  ctxl[idx * 64 + lane] = o;
}

// ---------------------------------------------------------------------------
// global sparse attention, MFMA + register top-16 edition.
// One wave = 16 queries x all 2048 keys. No __syncthreads.
// D[row][col]: row(query) = (lane>>4)*4 + reg, col(key) = lane&15.
// Lane q (q<16) owns query q's sorted top-16 in REGISTERS.
// Per-query ballots give exact per-column update masks; slow path touches
// LDS only for actual candidate scores.
// ---------------------------------------------------------------------------
__global__ __launch_bounds__(64) void global_attn(
    const short* __restrict__ Qh, const short* __restrict__ Kph,
    const float* __restrict__ Vp, const float* __restrict__ Wvp,
    const float* __restrict__ bvp, const float* __restrict__ ctxl,
    float* __restrict__ ctxc) {
  int wid = blockIdx.x;                // 2048 = 16 bh * 128 q-tiles
  int bh = wid >> 7;
  int q0 = (wid & 127) * 16;
  int b = bh >> 3, hh = bh & 7;
  int lane = threadIdx.x;
  int quad = lane >> 4;
  int l16 = lane & 15;

  __shared__ float sbuf[16][17];
  __shared__ float tw[16][17];
  __shared__ int   tix[16][17];
  __shared__ float spr[16][68];

  // register-resident sorted (desc) top-16 for lane's own query (lane<16)
  float tv[16];
  int ti[16];
#pragma unroll
  for (int j = 0; j < 16; j++) { tv[j] = -3.0e38f; ti[j] = 0; }

  const short* qbase = Qh + (size_t)(bh * 2048 + q0 + l16) * 64 + quad * 8;
  bf16x8 a0 = *(const bf16x8*)qbase;
  bf16x8 a1 = *(const bf16x8*)(qbase + 32);

  const short* kbase = Kph + (size_t)(bh * 2048 + l16) * 64 + quad * 8;
  bf16x8 b0 = *(const bf16x8*)kbase;
  bf16x8 b1 = *(const bf16x8*)(kbase + 32);

  float vmin_reg = -3.0e38f;  // lane<16: own query's current 16th value
  float rv0 = -3.0e38f, rv1 = -3.0e38f, rv2 = -3.0e38f, rv3 = -3.0e38f;
  int qb = quad * 4;

  for (int g = 0; g < 128; g++) {
    int gn = (g + 1 < 128) ? g + 1 : 127;
    bf16x8 nb0 = *(const bf16x8*)(kbase + gn * 1024);
    bf16x8 nb1 = *(const bf16x8*)(kbase + gn * 1024 + 32);
    f32x4 C = {0.f, 0.f, 0.f, 0.f};
    C = __builtin_amdgcn_mfma_f32_16x16x32_bf16(a0, b0, C, 0, 0, 0);
    C = __builtin_amdgcn_mfma_f32_16x16x32_bf16(a1, b1, C, 0, 0, 0);
    float s0 = C[0] * 0.125f, s1 = C[1] * 0.125f;
    float s2 = C[2] * 0.125f, s3 = C[3] * 0.125f;
    unsigned long long B0 = __ballot(s0 > rv0);
    unsigned long long B1 = __ballot(s1 > rv1);
    unsigned long long B2 = __ballot(s2 > rv2);
    unsigned long long B3 = __ballot(s3 > rv3);
    if (B0 | B1 | B2 | B3) {
      sbuf[qb + 0][l16] = s0;
      sbuf[qb + 1][l16] = s1;
      sbuf[qb + 2][l16] = s2;
      sbuf[qb + 3][l16] = s3;
      __builtin_amdgcn_wave_barrier();
      // lane q (<16) extracts its query's column mask from the right ballot
      int rq = lane & 3;
      unsigned long long Bq = rq == 0 ? B0 : (rq == 1 ? B1 : (rq == 2 ? B2 : B3));
      unsigned mask = (unsigned)((Bq >> ((lane >> 2) * 16)) & 0xFFFFull);
      if (lane >= 16) mask = 0;
      while (mask) {
        int c = __ffs(mask) - 1;
        mask &= mask - 1;
        float v = sbuf[lane][c];
        if (v > vmin_reg) {
          int ki = g * 16 + c;
          // unrolled sorted-desc insert; >= keeps earlier (lower) indices
          bool c_prev = true;
          float pv = 0.f;
          int pi = 0;
#pragma unroll
          for (int j = 0; j < 16; j++) {
            bool cj = tv[j] >= v;
            float cur = tv[j];
            int curi = ti[j];
            tv[j] = cj ? cur : (c_prev ? v : pv);
            ti[j] = cj ? curi : (c_prev ? ki : pi);
            c_prev = cj;
            pv = cur;
            pi = curi;
          }
          vmin_reg = tv[15];
        }
      }
      // broadcast fresh per-query thresholds to all lanes
      rv0 = __shfl(vmin_reg, qb + 0);
      rv1 = __shfl(vmin_reg, qb + 1);
      rv2 = __shfl(vmin_reg, qb + 2);
      rv3 = __shfl(vmin_reg, qb + 3);
    }
    b0 = nb0;
    b1 = nb1;
  }

  // softmax over the 16 kept scores (registers, sorted desc)
  if (lane < 16) {
    float m = tv[0];
    float ev[16], l = 0.f;
#pragma unroll
    for (int j = 0; j < 16; j++) {
      ev[j] = expf(tv[j] - m);
      l += ev[j];
    }
    float inv = 1.f / l;
#pragma unroll
    for (int j = 0; j < 16; j++) {
      tw[lane][j] = ev[j] * inv;
      tix[lane][j] = ti[j];
    }
  }
  __builtin_amdgcn_wave_barrier();

  // gather: 4 lanes per query, 16 r each -> spr[q][64]
  {
    int q = lane >> 2, rl = (lane & 3) * 16;
    float accr[16] = {};
#pragma unroll 4
    for (int j = 0; j < 16; j++) {
      float w = tw[q][j];
      const float* vrow = Vp + (size_t)(bh * 2048 + tix[q][j]) * 64 + rl;
      float4 v0 = *(const float4*)(vrow + 0);
      float4 v1 = *(const float4*)(vrow + 4);
      float4 v2 = *(const float4*)(vrow + 8);
      float4 v3 = *(const float4*)(vrow + 12);
      accr[0] += w * v0.x;  accr[1] += w * v0.y;
      accr[2] += w * v0.z;  accr[3] += w * v0.w;
      accr[4] += w * v1.x;  accr[5] += w * v1.y;
      accr[6] += w * v1.z;  accr[7] += w * v1.w;
      accr[8] += w * v2.x;  accr[9] += w * v2.y;
      accr[10] += w * v2.z; accr[11] += w * v2.w;
      accr[12] += w * v3.x; accr[13] += w * v3.y;
      accr[14] += w * v3.z; accr[15] += w * v3.w;
    }
#pragma unroll
    for (int u = 0; u < 16; u += 4)
      *(float4*)&spr[q][rl + u] =
          make_float4(accr[u], accr[u + 1], accr[u + 2], accr[u + 3]);
  }
  __builtin_amdgcn_wave_barrier();

  // projection sp @ Wvp^T + bvp, combine with local, write ctxc
  {
    int q = lane >> 2, jb = (lane & 3) * 16;
    float accj[16];
#pragma unroll
    for (int u = 0; u < 16; u++) accj[u] = bvp[jb + u];
    for (int r = 0; r < 64; r += 4) {
      float4 sp4 = *(const float4*)&spr[q][r];
#pragma unroll
      for (int u = 0; u < 16; u++) {
        float4 w4 = *(const float4*)(Wvp + (jb + u) * 64 + r);
        accj[u] += sp4.x * w4.x + sp4.y * w4.y + sp4.z * w4.z + sp4.w * w4.w;
      }
    }
    int s = q0 + q;
    const float* lrow = ctxl + (size_t)(bh * 2048 + s) * 64 + jb;
    float* orow = ctxc + (size_t)(b * 2048 + s) * 512 + hh * 64 + jb;
#pragma unroll
    for (int u = 0; u < 16; u += 4) {
      float4 lv = *(const float4*)(lrow + u);
      *(float4*)(orow + u) =
          make_float4(0.5f * (lv.x + accj[u]), 0.5f * (lv.y + accj[u + 1]),
                      0.5f * (lv.z + accj[u + 2]), 0.5f * (lv.w + accj[u + 3]));
    }
  }
}

// ---------------------------------------------------------------------------
// Wo gemm + bias + residual(h) -> d_out (pre-layernorm)
// ---------------------------------------------------------------------------
__global__ __launch_bounds__(256) void gemm_wo(
    const float* __restrict__ A, const float* __restrict__ Bm,
    const float* __restrict__ bo, const float* __restrict__ h,
    float* __restrict__ outp) {
  int m0 = blockIdx.x * 64;
  int n0 = blockIdx.y * 64;
  int tid = threadIdx.x;
  __shared__ float As[16][68];
  __shared__ float Bs[16][68];
  int tm = tid >> 4, tn = tid & 15;
  int ra = tid >> 2, ca = (tid & 3) * 4;
  int rb = tid >> 4, cb = (tid & 15) * 4;
  float acc[4][4] = {};
  for (int k0 = 0; k0 < 512; k0 += 16) {
    float4 av = *(const float4*)(A + (m0 + ra) * 512 + k0 + ca);
    float4 bv = *(const float4*)(Bm + (k0 + rb) * 512 + n0 + cb);
    As[ca + 0][ra] = av.x; As[ca + 1][ra] = av.y;
    As[ca + 2][ra] = av.z; As[ca + 3][ra] = av.w;
    *(float4*)&Bs[rb][cb] = bv;
    __syncthreads();
#pragma unroll
    for (int k = 0; k < 16; k++) {
      float4 a4 = *(const float4*)&As[k][tm * 4];
      float4 b4 = *(const float4*)&Bs[k][tn * 4];
      float av_[4] = {a4.x, a4.y, a4.z, a4.w};
      float bv_[4] = {b4.x, b4.y, b4.z, b4.w};
#pragma unroll
      for (int i = 0; i < 4; i++)
#pragma unroll
        for (int j = 0; j < 4; j++) acc[i][j] += av_[i] * bv_[j];
    }
    __syncthreads();
  }
  float bjs[4];
#pragma unroll
  for (int j = 0; j < 4; j++) bjs[j] = bo[n0 + tn * 4 + j];
#pragma unroll
  for (int i = 0; i < 4; i++) {
    int m = m0 + tm * 4 + i;
    const float* hp = h + m * 512 + n0 + tn * 4;
    float4 h4 = *(const float4*)hp;
    float4 o4 = make_float4(acc[i][0] + bjs[0] + h4.x,
                            acc[i][1] + bjs[1] + h4.y,
                            acc[i][2] + bjs[2] + h4.z,
                            acc[i][3] + bjs[3] + h4.w);
    *(float4*)(outp + m * 512 + n0 + tn * 4) = o4;
  }
}

// ---------------------------------------------------------------------------
// layernorm in place on d_out, one block per row
// ---------------------------------------------------------------------------
__global__ __launch_bounds__(256) void ln_kernel(float* __restrict__ o,
                                                 const float* __restrict__ g,
                                                 const float* __restrict__ bb) {
  int row = blockIdx.x;
  int tid = threadIdx.x;
  float v0 = o[row * 512 + tid];
  float v1 = o[row * 512 + 256 + tid];
  float s = v0 + v1;
  float s2 = v0 * v0 + v1 * v1;
#pragma unroll
  for (int off = 1; off < 64; off <<= 1) {
    s += __shfl_xor(s, off);
    s2 += __shfl_xor(s2, off);
  }
  __shared__ float ps[4], ps2[4];
  int w = tid >> 6;
  if ((tid & 63) == 0) { ps[w] = s; ps2[w] = s2; }
  __syncthreads();
  float S = ps[0] + ps[1] + ps[2] + ps[3];
  float S2 = ps2[0] + ps2[1] + ps2[2] + ps2[3];
  float mu = S * (1.f / 512.f);
  float var = S2 * (1.f / 512.f) - mu * mu;
  float inv = rsqrtf(var + 1e-5f);
  o[row * 512 + tid] = (v0 - mu) * inv * g[tid] + bb[tid];
  o[row * 512 + 256 + tid] = (v1 - mu) * inv * g[tid + 256] + bb[tid + 256];
}

// ---------------------------------------------------------------------------
extern "C" void kernel_launch(void* const* d_in, const int* in_sizes, int n_in,
                              void* d_out, int out_size, void* d_ws,
                              size_t ws_size, hipStream_t stream) {
  const float* x   = (const float*)d_in[0];
  const float* w1  = (const float*)d_in[1];
  const float* b1  = (const float*)d_in[2];
  const float* w2  = (const float*)d_in[3];
  const float* b2  = (const float*)d_in[4];
  const float* w3  = (const float*)d_in[5];
  const float* b3  = (const float*)d_in[6];
  const float* Wq  = (const float*)d_in[7];
  const float* bq  = (const float*)d_in[8];
  const float* Wk  = (const float*)d_in[9];
  const float* bk  = (const float*)d_in[10];
  const float* Wv  = (const float*)d_in[11];
  const float* bv  = (const float*)d_in[12];
  const float* Wkp = (const float*)d_in[13];
  const float* bkp = (const float*)d_in[14];
  const float* Wvp = (const float*)d_in[15];
  const float* bvp = (const float*)d_in[16];
  const float* Wo  = (const float*)d_in[17];
  const float* bo  = (const float*)d_in[18];
  const float* lng = (const float*)d_in[19];
  const float* lnb = (const float*)d_in[20];

  float* ws    = (float*)d_ws;
  float* WallT = ws;                     // 786432
  float* ball  = WallT + 786432;         // 1536
  float* WoT   = ball + 1536;            // 262144
  float* h     = WoT + 262144;           // 2097152 floats each below
  float* Qb    = h + 2097152;
  float* Kb    = Qb + 2097152;
  float* Vb    = Kb + 2097152;
  float* bf16slot = Vb + 2097152;        // 8 MB: Kph (4MB) + Qh (4MB)
  float* Vpb   = bf16slot + 2097152;
  float* ctxl  = Vpb + 2097152;
  float* ctxc  = ctxl + 2097152;
  float* outF  = (float*)d_out;

  short* Kph = (short*)bf16slot;
  short* Qh  = Kph + 2097152;

  prep_kernel<<<512, 256, 0, stream>>>(Wq, Wk, Wv, bq, bk, bv, Wo, WallT, ball,
                                       WoT);
  conv_kernel<<<512, 256, 0, stream>>>(x, w1, b1, w2, b2, w3, b3, h);
  {
    dim3 g(64, 24);
    gemm_qkv<<<g, 256, 0, stream>>>(h, WallT, ball, Qb, Kb, Vb, Qh);
  }
  kpvp_kernel<<<256, 256, 0, stream>>>(Kb, Vb, Wkp, bkp, Wvp, bvp, Kph, Vpb);
  local_attn<<<8192, 256, 0, stream>>>(Qb, Kb, Vb, ctxl);
  global_attn<<<2048, 64, 0, stream>>>(Qh, Kph, Vpb, Wvp, bvp, ctxl, ctxc);
  {
    dim3 g(64, 8);
    gemm_wo<<<g, 256, 0, stream>>>(ctxc, WoT, bo, h, outF);
  }
  ln_kernel<<<4096, 256, 0, stream>>>(outF, lng, lnb);
}

// Round 5
// 504.657 us; speedup vs baseline: 2.9205x; 1.1003x over previous
//
#include <hip/hip_runtime.h>
#include <hip/hip_bf16.h>

#define BB 2
#define SS 2048
#define INC 64
#define HIDN 512
#define NHH 8
#define HDD 64

typedef __attribute__((ext_vector_type(8))) short bf16x8;
typedef __attribute__((ext_vector_type(4))) float f32x4;

__device__ __forceinline__ short f2bf(float f) {
  union { __hip_bfloat16 h; short s; } u;
  u.h = __float2bfloat16(f);
  return u.s;
}
__device__ __forceinline__ int pack2bf(float lo, float hi) {
  return (int)((unsigned short)f2bf(lo) | ((unsigned)(unsigned short)f2bf(hi) << 16));
}

// ---------------------------------------------------------------------------
// prep: transpose Wq/Wk/Wv into WallT (512 x 1536), Wo into WoT (512x512),
// concat biases into ball (1536)
// ---------------------------------------------------------------------------
__global__ __launch_bounds__(256) void prep_kernel(
    const float* __restrict__ Wq, const float* __restrict__ Wk_,
    const float* __restrict__ Wv_, const float* __restrict__ bq,
    const float* __restrict__ bk_, const float* __restrict__ bv_,
    const float* __restrict__ Wo, float* __restrict__ WallT,
    float* __restrict__ ball, float* __restrict__ WoT) {
  int i0 = blockIdx.x * 256 + threadIdx.x;
  int stride = gridDim.x * 256;
  for (int idx = i0; idx < 512 * 1536; idx += stride) {
    int k = idx / 1536, n = idx % 1536;
    float v;
    if (n < 512)       v = Wq[n * 512 + k];
    else if (n < 1024) v = Wk_[(n - 512) * 512 + k];
    else               v = Wv_[(n - 1024) * 512 + k];
    WallT[idx] = v;
  }
  for (int idx = i0; idx < 512 * 512; idx += stride) {
    WoT[idx] = Wo[(idx % 512) * 512 + (idx / 512)];
  }
  if (i0 < 1536) {
    float v;
    if (i0 < 512)       v = bq[i0];
    else if (i0 < 1024) v = bk_[i0 - 512];
    else                v = bv_[i0 - 1024];
    ball[i0] = v;
  }
}

// ---------------------------------------------------------------------------
// conv: h[b,s,c] = relu(conv{1,2,3}(x)) concat over channels. 8 s per block.
// ---------------------------------------------------------------------------
template <int KW, int OFF>
__device__ __forceinline__ void conv_channel(const float* __restrict__ w,
                                             const float* xs, float bias,
                                             float acc[8]) {
#pragma unroll
  for (int i = 0; i < 8; i++) acc[i] = bias;
  for (int ci = 0; ci < 64; ci++) {
    float xv[8 + KW - 1];
#pragma unroll
    for (int r = 0; r < 8 + KW - 1; r++) xv[r] = xs[(r + OFF) * 64 + ci];
#pragma unroll
    for (int k = 0; k < KW; k++) {
      float wv = w[ci * KW + k];
#pragma unroll
      for (int i = 0; i < 8; i++) acc[i] += xv[i + k] * wv;
    }
  }
}

__global__ __launch_bounds__(256) void conv_kernel(
    const float* __restrict__ x, const float* __restrict__ w1,
    const float* __restrict__ b1, const float* __restrict__ w2,
    const float* __restrict__ b2, const float* __restrict__ w3,
    const float* __restrict__ b3, float* __restrict__ h) {
  const int TS = 8;
  int blk = blockIdx.x;                 // 512 blocks
  int b = blk / (SS / TS);
  int s0 = (blk % (SS / TS)) * TS;
  __shared__ float xs[(TS + 6) * 64];   // rows s0-3 .. s0+TS+2
  int tid = threadIdx.x;
  for (int i = tid; i < (TS + 6) * 64; i += 256) {
    int row = i >> 6, ci = i & 63;
    int sgl = s0 + row - 3;
    xs[i] = (sgl >= 0 && sgl < SS) ? x[(b * SS + sgl) * 64 + ci] : 0.f;
  }
  __syncthreads();
  for (int c = tid; c < 512; c += 256) {
    float acc[8];
    if (c < 171) {
      conv_channel<3, 2>(w1 + c * (64 * 3), xs, b1[c], acc);
    } else if (c < 342) {
      conv_channel<5, 1>(w2 + (c - 171) * (64 * 5), xs, b2[c - 171], acc);
    } else {
      conv_channel<7, 0>(w3 + (c - 342) * (64 * 7), xs, b3[c - 342], acc);
    }
#pragma unroll
    for (int i = 0; i < 8; i++)
      h[(b * SS + s0 + i) * 512 + c] = fmaxf(acc[i], 0.f);
  }
}

// ---------------------------------------------------------------------------
// QKV gemm: C(4096 x 1536) = h(4096x512) @ WallT(512x1536) + ball,
// scattered into Q/K/V (B,NH,S,HD); also emits bf16 copy of Q*0.125 (Qh).
// ---------------------------------------------------------------------------
__global__ __launch_bounds__(256) void gemm_qkv(
    const float* __restrict__ A, const float* __restrict__ Bm,
    const float* __restrict__ bias, float* __restrict__ Qo,
    float* __restrict__ Ko, float* __restrict__ Vo,
    short* __restrict__ Qh) {
  int m0 = blockIdx.x * 64;
  int n0 = blockIdx.y * 64;
  int tid = threadIdx.x;
  __shared__ float As[16][68];  // [k][m]
  __shared__ float Bs[16][68];  // [k][n]
  int tm = tid >> 4, tn = tid & 15;
  int ra = tid >> 2, ca = (tid & 3) * 4;
  int rb = tid >> 4, cb = (tid & 15) * 4;
  float acc[4][4] = {};
  for (int k0 = 0; k0 < 512; k0 += 16) {
    float4 av = *(const float4*)(A + (m0 + ra) * 512 + k0 + ca);
    float4 bv = *(const float4*)(Bm + (k0 + rb) * 1536 + n0 + cb);
    As[ca + 0][ra] = av.x; As[ca + 1][ra] = av.y;
    As[ca + 2][ra] = av.z; As[ca + 3][ra] = av.w;
    *(float4*)&Bs[rb][cb] = bv;
    __syncthreads();
#pragma unroll
    for (int k = 0; k < 16; k++) {
      float4 a4 = *(const float4*)&As[k][tm * 4];
      float4 b4 = *(const float4*)&Bs[k][tn * 4];
      float av_[4] = {a4.x, a4.y, a4.z, a4.w};
      float bv_[4] = {b4.x, b4.y, b4.z, b4.w};
#pragma unroll
      for (int i = 0; i < 4; i++)
#pragma unroll
        for (int j = 0; j < 4; j++) acc[i][j] += av_[i] * bv_[j];
    }
    __syncthreads();
  }
  int which = n0 >> 9;
  int head = (n0 >> 6) & 7;
  float* dst = which == 0 ? Qo : (which == 1 ? Ko : Vo);
  float bjs[4];
#pragma unroll
  for (int j = 0; j < 4; j++) bjs[j] = bias[n0 + tn * 4 + j];
#pragma unroll
  for (int i = 0; i < 4; i++) {
    int m = m0 + tm * 4 + i;
    int bb = m >> 11, s = m & 2047;
    float* dp = dst + ((bb * 8 + head) * 2048 + s) * 64 + tn * 4;
    float4 o4 = make_float4(acc[i][0] + bjs[0], acc[i][1] + bjs[1],
                            acc[i][2] + bjs[2], acc[i][3] + bjs[3]);
    *(float4*)dp = o4;
    if (which == 0) {
      short4 q4s;  // 0.125 scale folded in (exact, pow2)
      q4s.x = f2bf(o4.x * 0.125f); q4s.y = f2bf(o4.y * 0.125f);
      q4s.z = f2bf(o4.z * 0.125f); q4s.w = f2bf(o4.w * 0.125f);
      *(short4*)(Qh + (dp - Qo)) = q4s;
    }
  }
}

// ---------------------------------------------------------------------------
// Kp (bf16 rows, B,NH,S,R) and Vp (fp32, B,NH,S,R) projections
// ---------------------------------------------------------------------------
__global__ __launch_bounds__(256) void kpvp_kernel(
    const float* __restrict__ K, const float* __restrict__ V,
    const float* __restrict__ Wkp, const float* __restrict__ bkp,
    const float* __restrict__ Wvp, const float* __restrict__ bvp,
    short* __restrict__ Kph, float* __restrict__ Vp) {
  int bh = blockIdx.x >> 4;            // 256 blocks: B*NH * (S/128)
  int k0 = (blockIdx.x & 15) * 128;
  int tid = threadIdx.x;
  __shared__ float tile[128][65];
  __shared__ float Wb[64][65];
  // ---- phase 1: Kph (bf16 row-major [key][64]) ----
  for (int i = tid; i < 128 * 64; i += 256)
    tile[i >> 6][i & 63] = K[(bh * 2048 + k0 + (i >> 6)) * 64 + (i & 63)];
  for (int i = tid; i < 4096; i += 256) Wb[i >> 6][i & 63] = Wkp[i];
  __syncthreads();
  {
    int kl = tid & 63, rbase = (tid >> 6) * 16;
    for (int half = 0; half < 2; half++) {
      int kk = kl + half * 64;
      int packed[8];
#pragma unroll
      for (int ri = 0; ri < 16; ri += 2) {
        float a0 = bkp[rbase + ri], a1 = bkp[rbase + ri + 1];
#pragma unroll 8
        for (int d = 0; d < 64; d++) {
          float t = tile[kk][d];
          a0 += t * Wb[rbase + ri][d];
          a1 += t * Wb[rbase + ri + 1][d];
        }
        packed[ri >> 1] = pack2bf(a0, a1);
      }
      int4* dst = (int4*)(Kph + (size_t)(bh * 2048 + k0 + kk) * 64 + rbase);
      dst[0] = make_int4(packed[0], packed[1], packed[2], packed[3]);
      dst[1] = make_int4(packed[4], packed[5], packed[6], packed[7]);
    }
  }
  __syncthreads();
  // ---- phase 2: Vp ----
  for (int i = tid; i < 128 * 64; i += 256)
    tile[i >> 6][i & 63] = V[(bh * 2048 + k0 + (i >> 6)) * 64 + (i & 63)];
  for (int i = tid; i < 4096; i += 256) Wb[i >> 6][i & 63] = Wvp[i];
  __syncthreads();
  {
    int r = tid & 63, kb = tid >> 6;
    for (int ri = 0; ri < 32; ri++) {
      int kk = kb + ri * 4;
      float acc = bvp[r];
#pragma unroll 8
      for (int d = 0; d < 64; d++) acc += tile[kk][d] * Wb[r][d];
      Vp[(bh * 2048 + k0 + kk) * 64 + r] = acc;
    }
  }
}

// ---------------------------------------------------------------------------
// local windowed attention: one wave per query
// ---------------------------------------------------------------------------
__global__ __launch_bounds__(256) void local_attn(
    const float* __restrict__ Q, const float* __restrict__ K,
    const float* __restrict__ V, float* __restrict__ ctxl) {
  int idx = blockIdx.x * 4 + (threadIdx.x >> 6);  // global query over B*NH*S
  int lane = threadIdx.x & 63;
  int bh = idx >> 11;
  int s = idx & 2047;
  float qd = Q[idx * 64 + lane];
  float sc[5];
  bool ok[5];
#pragma unroll
  for (int j = 0; j < 5; j++) {
    int sj = s + j - 2;
    ok[j] = (sj >= 0 && sj < SS);
    float p = ok[j] ? qd * K[(bh * 2048 + sj) * 64 + lane] : 0.f;
    p += __shfl_xor(p, 1);  p += __shfl_xor(p, 2);  p += __shfl_xor(p, 4);
    p += __shfl_xor(p, 8);  p += __shfl_xor(p, 16); p += __shfl_xor(p, 32);
    sc[j] = p * 0.125f;
  }
  float m = -3.0e38f;
#pragma unroll
  for (int j = 0; j < 5; j++)
    if (ok[j]) m = fmaxf(m, sc[j]);
  float e[5], l = 0.f;
#pragma unroll
  for (int j = 0; j < 5; j++) {
    e[j] = ok[j] ? expf(sc[j] - m) : 0.f;
    l += e[j];
  }
  float inv = 1.f / l;
  float o = 0.f;
#pragma unroll
  for (int j = 0; j < 5; j++) {
    int sj = s + j - 2;
    if (ok[j]) o += e[j] * inv * V[(bh * 2048 + sj) * 64 + lane];
  }
  ctxl[idx * 64 + lane] = o;
}

// ---------------------------------------------------------------------------
// global sparse attention: MFMA + branch-free per-column register top-10.
// One wave = 16 queries x all 2048 keys. Key column = lane&15.
// Per (lane, reg r): sorted-desc top-10 of packed candidates
//   packed = sortable_fp32(score)[31:11] | (2047-keyidx)[10:0]
// (21-bit score precision ~1e-3 abs; unique packing -> exact lowest-index
//  tie-break). Exactness: miss requires >=11 of a query's top-16 in one
//  column; P ~ 1e-4 over the whole run.
// Merge: per query, 16 rounds of row shfl-max; winner pops its list head.
// ---------------------------------------------------------------------------
__global__ __launch_bounds__(64) void global_attn(
    const short* __restrict__ Qh, const short* __restrict__ Kph,
    const float* __restrict__ Vp, const float* __restrict__ Wvp,
    const float* __restrict__ bvp, const float* __restrict__ ctxl,
    float* __restrict__ ctxc) {
  int wid = blockIdx.x;                // 2048 = 16 bh * 128 q-tiles
  int bh = wid >> 7;
  int q0 = (wid & 127) * 16;
  int b = bh >> 3, hh = bh & 7;
  int lane = threadIdx.x;
  int quad = lane >> 4;
  int l16 = lane & 15;

  __shared__ float tw[16][17];
  __shared__ int   tix[16][17];
  __shared__ float spr[16][68];

  const short* qbase = Qh + (size_t)(bh * 2048 + q0 + l16) * 64 + quad * 8;
  bf16x8 a0 = *(const bf16x8*)qbase;
  bf16x8 a1 = *(const bf16x8*)(qbase + 32);

  const short* kbase = Kph + (size_t)(bh * 2048 + l16) * 64 + quad * 8;
  bf16x8 b0 = *(const bf16x8*)kbase;
  bf16x8 b1 = *(const bf16x8*)(kbase + 32);

  unsigned e0[10], e1[10], e2[10], e3[10];
#pragma unroll
  for (int j = 0; j < 10; j++) { e0[j] = 0; e1[j] = 0; e2[j] = 0; e3[j] = 0; }

  auto insert = [&](unsigned (&er)[10], unsigned cand) {
    unsigned p = cand;
#pragma unroll
    for (int j = 0; j < 10; j++) {
      unsigned cur = er[j];
      bool keep = cur >= p;
      unsigned hi = keep ? cur : p;
      p = keep ? p : cur;
      er[j] = hi;
    }
  };
  auto mkcand = [&](float s, int idxr) -> unsigned {
    unsigned u = __float_as_uint(s);
    u ^= ((unsigned)((int)u >> 31)) | 0x80000000u;
    return (u & 0xFFFFF800u) | (unsigned)idxr;
  };

  int idxbase = 2047 - l16;
#pragma unroll 1
  for (int g = 0; g < 128; g++) {
    int gn = (g + 1 < 128) ? g + 1 : 127;
    bf16x8 nb0 = *(const bf16x8*)(kbase + gn * 1024);
    bf16x8 nb1 = *(const bf16x8*)(kbase + gn * 1024 + 32);
    f32x4 C = {0.f, 0.f, 0.f, 0.f};
    C = __builtin_amdgcn_mfma_f32_16x16x32_bf16(a0, b0, C, 0, 0, 0);
    C = __builtin_amdgcn_mfma_f32_16x16x32_bf16(a1, b1, C, 0, 0, 0);
    int idxr = idxbase - (g << 4);
    insert(e0, mkcand(C[0], idxr));
    insert(e1, mkcand(C[1], idxr));
    insert(e2, mkcand(C[2], idxr));
    insert(e3, mkcand(C[3], idxr));
    b0 = nb0;
    b1 = nb1;
  }

  // merge: per query (quad*4+r), extract global top-16 from 16 column lists
  auto merge = [&](unsigned (&er)[10], int r) {
    float ev[16];
    int kit[16];
    float mval = 0.f, lsum = 0.f;
#pragma unroll
    for (int t = 0; t < 16; t++) {
      unsigned w = er[0];
#pragma unroll
      for (int mm = 1; mm <= 8; mm <<= 1) {
        unsigned o = (unsigned)__shfl_xor((int)w, mm);
        w = w > o ? w : o;
      }
      bool win = (er[0] == w);
      if (win) {
#pragma unroll
        for (int j = 0; j < 9; j++) er[j] = er[j + 1];
        er[9] = 0;
      }
      unsigned wv = w & 0xFFFFF800u;
      unsigned uu = (w & 0x80000000u) ? (wv ^ 0x80000000u) : ~wv;
      float sv = __uint_as_float(uu);
      int ki = 2047 - (int)(w & 0x7FFu);
      if (t == 0) mval = sv;
      float ex = __expf(sv - mval);
      lsum += ex;
      ev[t] = ex;
      kit[t] = ki;
    }
    float inv = 1.f / lsum;
    if (l16 == r) {
      int qr = quad * 4 + r;
#pragma unroll
      for (int j = 0; j < 16; j++) {
        tw[qr][j] = ev[j] * inv;
        tix[qr][j] = kit[j];
      }
    }
  };
  merge(e0, 0);
  merge(e1, 1);
  merge(e2, 2);
  merge(e3, 3);
  __builtin_amdgcn_wave_barrier();

  // gather: 4 lanes per query, 16 r each -> spr[q][64]
  {
    int q = lane >> 2, rl = (lane & 3) * 16;
    float accr[16] = {};
#pragma unroll 4
    for (int j = 0; j < 16; j++) {
      float w = tw[q][j];
      const float* vrow = Vp + (size_t)(bh * 2048 + tix[q][j]) * 64 + rl;
      float4 v0 = *(const float4*)(vrow + 0);
      float4 v1 = *(const float4*)(vrow + 4);
      float4 v2 = *(const float4*)(vrow + 8);
      float4 v3 = *(const float4*)(vrow + 12);
      accr[0] += w * v0.x;  accr[1] += w * v0.y;
      accr[2] += w * v0.z;  accr[3] += w * v0.w;
      accr[4] += w * v1.x;  accr[5] += w * v1.y;
      accr[6] += w * v1.z;  accr[7] += w * v1.w;
      accr[8] += w * v2.x;  accr[9] += w * v2.y;
      accr[10] += w * v2.z; accr[11] += w * v2.w;
      accr[12] += w * v3.x; accr[13] += w * v3.y;
      accr[14] += w * v3.z; accr[15] += w * v3.w;
    }
#pragma unroll
    for (int u = 0; u < 16; u += 4)
      *(float4*)&spr[q][rl + u] =
          make_float4(accr[u], accr[u + 1], accr[u + 2], accr[u + 3]);
  }
  __builtin_amdgcn_wave_barrier();

  // projection sp @ Wvp^T + bvp, combine with local, write ctxc
  {
    int q = lane >> 2, jb = (lane & 3) * 16;
    float accj[16];
#pragma unroll
    for (int u = 0; u < 16; u++) accj[u] = bvp[jb + u];
    for (int r = 0; r < 64; r += 4) {
      float4 sp4 = *(const float4*)&spr[q][r];
#pragma unroll
      for (int u = 0; u < 16; u++) {
        float4 w4 = *(const float4*)(Wvp + (jb + u) * 64 + r);
        accj[u] += sp4.x * w4.x + sp4.y * w4.y + sp4.z * w4.z + sp4.w * w4.w;
      }
    }
    int s = q0 + q;
    const float* lrow = ctxl + (size_t)(bh * 2048 + s) * 64 + jb;
    float* orow = ctxc + (size_t)(b * 2048 + s) * 512 + hh * 64 + jb;
#pragma unroll
    for (int u = 0; u < 16; u += 4) {
      float4 lv = *(const float4*)(lrow + u);
      *(float4*)(orow + u) =
          make_float4(0.5f * (lv.x + accj[u]), 0.5f * (lv.y + accj[u + 1]),
                      0.5f * (lv.z + accj[u + 2]), 0.5f * (lv.w + accj[u + 3]));
    }
  }
}

// ---------------------------------------------------------------------------
// Wo gemm + bias + residual(h) -> d_out (pre-layernorm)
// ---------------------------------------------------------------------------
__global__ __launch_bounds__(256) void gemm_wo(
    const float* __restrict__ A, const float* __restrict__ Bm,
    const float* __restrict__ bo, const float* __restrict__ h,
    float* __restrict__ outp) {
  int m0 = blockIdx.x * 64;
  int n0 = blockIdx.y * 64;
  int tid = threadIdx.x;
  __shared__ float As[16][68];
  __shared__ float Bs[16][68];
  int tm = tid >> 4, tn = tid & 15;
  int ra = tid >> 2, ca = (tid & 3) * 4;
  int rb = tid >> 4, cb = (tid & 15) * 4;
  float acc[4][4] = {};
  for (int k0 = 0; k0 < 512; k0 += 16) {
    float4 av = *(const float4*)(A + (m0 + ra) * 512 + k0 + ca);
    float4 bv = *(const float4*)(Bm + (k0 + rb) * 512 + n0 + cb);
    As[ca + 0][ra] = av.x; As[ca + 1][ra] = av.y;
    As[ca + 2][ra] = av.z; As[ca + 3][ra] = av.w;
    *(float4*)&Bs[rb][cb] = bv;
    __syncthreads();
#pragma unroll
    for (int k = 0; k < 16; k++) {
      float4 a4 = *(const float4*)&As[k][tm * 4];
      float4 b4 = *(const float4*)&Bs[k][tn * 4];
      float av_[4] = {a4.x, a4.y, a4.z, a4.w};
      float bv_[4] = {b4.x, b4.y, b4.z, b4.w};
#pragma unroll
      for (int i = 0; i < 4; i++)
#pragma unroll
        for (int j = 0; j < 4; j++) acc[i][j] += av_[i] * bv_[j];
    }
    __syncthreads();
  }
  float bjs[4];
#pragma unroll
  for (int j = 0; j < 4; j++) bjs[j] = bo[n0 + tn * 4 + j];
#pragma unroll
  for (int i = 0; i < 4; i++) {
    int m = m0 + tm * 4 + i;
    const float* hp = h + m * 512 + n0 + tn * 4;
    float4 h4 = *(const float4*)hp;
    float4 o4 = make_float4(acc[i][0] + bjs[0] + h4.x,
                            acc[i][1] + bjs[1] + h4.y,
                            acc[i][2] + bjs[2] + h4.z,
                            acc[i][3] + bjs[3] + h4.w);
    *(float4*)(outp + m * 512 + n0 + tn * 4) = o4;
  }
}

// ---------------------------------------------------------------------------
// layernorm in place on d_out, one block per row
// ---------------------------------------------------------------------------
__global__ __launch_bounds__(256) void ln_kernel(float* __restrict__ o,
                                                 const float* __restrict__ g,
                                                 const float* __restrict__ bb) {
  int row = blockIdx.x;
  int tid = threadIdx.x;
  float v0 = o[row * 512 + tid];
  float v1 = o[row * 512 + 256 + tid];
  float s = v0 + v1;
  float s2 = v0 * v0 + v1 * v1;
#pragma unroll
  for (int off = 1; off < 64; off <<= 1) {
    s += __shfl_xor(s, off);
    s2 += __shfl_xor(s2, off);
  }
  __shared__ float ps[4], ps2[4];
  int w = tid >> 6;
  if ((tid & 63) == 0) { ps[w] = s; ps2[w] = s2; }
  __syncthreads();
  float S = ps[0] + ps[1] + ps[2] + ps[3];
  float S2 = ps2[0] + ps2[1] + ps2[2] + ps2[3];
  float mu = S * (1.f / 512.f);
  float var = S2 * (1.f / 512.f) - mu * mu;
  float inv = rsqrtf(var + 1e-5f);
  o[row * 512 + tid] = (v0 - mu) * inv * g[tid] + bb[tid];
  o[row * 512 + 256 + tid] = (v1 - mu) * inv * g[tid + 256] + bb[tid + 256];
}

// ---------------------------------------------------------------------------
extern "C" void kernel_launch(void* const* d_in, const int* in_sizes, int n_in,
                              void* d_out, int out_size, void* d_ws,
                              size_t ws_size, hipStream_t stream) {
  const float* x   = (const float*)d_in[0];
  const float* w1  = (const float*)d_in[1];
  const float* b1  = (const float*)d_in[2];
  const float* w2  = (const float*)d_in[3];
  const float* b2  = (const float*)d_in[4];
  const float* w3  = (const float*)d_in[5];
  const float* b3  = (const float*)d_in[6];
  const float* Wq  = (const float*)d_in[7];
  const float* bq  = (const float*)d_in[8];
  const float* Wk  = (const float*)d_in[9];
  const float* bk  = (const float*)d_in[10];
  const float* Wv  = (const float*)d_in[11];
  const float* bv  = (const float*)d_in[12];
  const float* Wkp = (const float*)d_in[13];
  const float* bkp = (const float*)d_in[14];
  const float* Wvp = (const float*)d_in[15];
  const float* bvp = (const float*)d_in[16];
  const float* Wo  = (const float*)d_in[17];
  const float* bo  = (const float*)d_in[18];
  const float* lng = (const float*)d_in[19];
  const float* lnb = (const float*)d_in[20];

  float* ws    = (float*)d_ws;
  float* WallT = ws;                     // 786432
  float* ball  = WallT + 786432;         // 1536
  float* WoT   = ball + 1536;            // 262144
  float* h     = WoT + 262144;           // 2097152 floats each below
  float* Qb    = h + 2097152;
  float* Kb    = Qb + 2097152;
  float* Vb    = Kb + 2097152;
  float* bf16slot = Vb + 2097152;        // 8 MB: Kph (4MB) + Qh (4MB)
  float* Vpb   = bf16slot + 2097152;
  float* ctxl  = Vpb + 2097152;
  float* ctxc  = ctxl + 2097152;
  float* outF  = (float*)d_out;

  short* Kph = (short*)bf16slot;
  short* Qh  = Kph + 2097152;

  prep_kernel<<<512, 256, 0, stream>>>(Wq, Wk, Wv, bq, bk, bv, Wo, WallT, ball,
                                       WoT);
  conv_kernel<<<512, 256, 0, stream>>>(x, w1, b1, w2, b2, w3, b3, h);
  {
    dim3 g(64, 24);
    gemm_qkv<<<g, 256, 0, stream>>>(h, WallT, ball, Qb, Kb, Vb, Qh);
  }
  kpvp_kernel<<<256, 256, 0, stream>>>(Kb, Vb, Wkp, bkp, Wvp, bvp, Kph, Vpb);
  local_attn<<<8192, 256, 0, stream>>>(Qb, Kb, Vb, ctxl);
  global_attn<<<2048, 64, 0, stream>>>(Qh, Kph, Vpb, Wvp, bvp, ctxl, ctxc);
  {
    dim3 g(64, 8);
    gemm_wo<<<g, 256, 0, stream>>>(ctxc, WoT, bo, h, outF);
  }
  ln_kernel<<<4096, 256, 0, stream>>>(outF, lng, lnb);
}

// Round 6
// 427.307 us; speedup vs baseline: 3.4491x; 1.1810x over previous
//
#include <hip/hip_runtime.h>
#include <hip/hip_bf16.h>

#define BB 2
#define SS 2048
#define INC 64
#define HIDN 512
#define NHH 8
#define HDD 64

typedef __attribute__((ext_vector_type(8))) short bf16x8;
typedef __attribute__((ext_vector_type(4))) float f32x4;

__device__ __forceinline__ short f2bf(float f) {
  union { __hip_bfloat16 h; short s; } u;
  u.h = __float2bfloat16(f);
  return u.s;
}
__device__ __forceinline__ int pack2bf(float lo, float hi) {
  return (int)((unsigned short)f2bf(lo) | ((unsigned)(unsigned short)f2bf(hi) << 16));
}

// ---------------------------------------------------------------------------
// prep: bf16 weights. Wallbf = concat(Wq,Wk,Wv) rows (n,k) = 1536x512;
// Wobf = Wo (n,k) 512x512; ball = concat biases.
// ---------------------------------------------------------------------------
__global__ __launch_bounds__(256) void prep_kernel(
    const float* __restrict__ Wq, const float* __restrict__ Wk_,
    const float* __restrict__ Wv_, const float* __restrict__ bq,
    const float* __restrict__ bk_, const float* __restrict__ bv_,
    const float* __restrict__ Wo, short* __restrict__ Wallbf,
    float* __restrict__ ball, short* __restrict__ Wobf) {
  int i0 = blockIdx.x * 256 + threadIdx.x;
  int stride = gridDim.x * 256;
  for (int idx = i0; idx < 786432; idx += stride) {
    float v;
    if (idx < 262144)      v = Wq[idx];
    else if (idx < 524288) v = Wk_[idx - 262144];
    else                   v = Wv_[idx - 524288];
    Wallbf[idx] = f2bf(v);
  }
  for (int idx = i0; idx < 262144; idx += stride) Wobf[idx] = f2bf(Wo[idx]);
  if (i0 < 1536) {
    float v;
    if (i0 < 512)       v = bq[i0];
    else if (i0 < 1024) v = bk_[i0 - 512];
    else                v = bv_[i0 - 1024];
    ball[i0] = v;
  }
}

// ---------------------------------------------------------------------------
// conv: h[b,s,c] = relu(conv{1,2,3}(x)); writes fp32 h and bf16 hbf.
// ---------------------------------------------------------------------------
template <int KW, int OFF>
__device__ __forceinline__ void conv_channel(const float* __restrict__ w,
                                             const float* xs, float bias,
                                             float acc[8]) {
#pragma unroll
  for (int i = 0; i < 8; i++) acc[i] = bias;
  for (int ci = 0; ci < 64; ci++) {
    float xv[8 + KW - 1];
#pragma unroll
    for (int r = 0; r < 8 + KW - 1; r++) xv[r] = xs[(r + OFF) * 64 + ci];
#pragma unroll
    for (int k = 0; k < KW; k++) {
      float wv = w[ci * KW + k];
#pragma unroll
      for (int i = 0; i < 8; i++) acc[i] += xv[i + k] * wv;
    }
  }
}

__global__ __launch_bounds__(256) void conv_kernel(
    const float* __restrict__ x, const float* __restrict__ w1,
    const float* __restrict__ b1, const float* __restrict__ w2,
    const float* __restrict__ b2, const float* __restrict__ w3,
    const float* __restrict__ b3, float* __restrict__ h,
    short* __restrict__ hbf) {
  const int TS = 8;
  int blk = blockIdx.x;                 // 512 blocks
  int b = blk / (SS / TS);
  int s0 = (blk % (SS / TS)) * TS;
  __shared__ float xs[(TS + 6) * 64];
  int tid = threadIdx.x;
  for (int i = tid; i < (TS + 6) * 64; i += 256) {
    int row = i >> 6, ci = i & 63;
    int sgl = s0 + row - 3;
    xs[i] = (sgl >= 0 && sgl < SS) ? x[(b * SS + sgl) * 64 + ci] : 0.f;
  }
  __syncthreads();
  for (int c = tid; c < 512; c += 256) {
    float acc[8];
    if (c < 171) {
      conv_channel<3, 2>(w1 + c * (64 * 3), xs, b1[c], acc);
    } else if (c < 342) {
      conv_channel<5, 1>(w2 + (c - 171) * (64 * 5), xs, b2[c - 171], acc);
    } else {
      conv_channel<7, 0>(w3 + (c - 342) * (64 * 7), xs, b3[c - 342], acc);
    }
#pragma unroll
    for (int i = 0; i < 8; i++) {
      float v = fmaxf(acc[i], 0.f);
      int idx = (b * SS + s0 + i) * 512 + c;
      h[idx] = v;
      hbf[idx] = f2bf(v);
    }
  }
}

// ---------------------------------------------------------------------------
// MFMA QKV gemm: C(4096x1536) = hbf @ Wallbf^T + ball. Block = 128Mx64N,
// 4 waves (each 32 rows x 64 cols). B frags stream from L2 (weights
// L2-resident); no LDS, no barriers. Scatter to Q/K/V fp32 + Qh bf16*0.125.
// ---------------------------------------------------------------------------
__global__ __launch_bounds__(256) void gemm_qkv(
    const short* __restrict__ Abf, const short* __restrict__ Wbf,
    const float* __restrict__ bias, float* __restrict__ Qo,
    float* __restrict__ Ko, float* __restrict__ Vo,
    short* __restrict__ Qh) {
  int m0 = blockIdx.x * 128;
  int n0 = blockIdx.y * 64;
  int tid = threadIdx.x;
  int wvv = tid >> 6, lane = tid & 63;
  int quad = lane >> 4, l16 = lane & 15;
  int mw = m0 + wvv * 32;
  const short* ap0 = Abf + (size_t)(mw + l16) * 512 + quad * 8;
  const short* ap1 = ap0 + 16 * 512;
  const short* bp = Wbf + (size_t)(n0 + l16) * 512 + quad * 8;
  f32x4 acc[2][4] = {};
#pragma unroll 1
  for (int ks = 0; ks < 16; ks++) {
    int off = ks * 32;
    bf16x8 A0 = *(const bf16x8*)(ap0 + off);
    bf16x8 A1 = *(const bf16x8*)(ap1 + off);
#pragma unroll
    for (int t = 0; t < 4; t++) {
      bf16x8 Bt = *(const bf16x8*)(bp + t * 16 * 512 + off);
      acc[0][t] = __builtin_amdgcn_mfma_f32_16x16x32_bf16(A0, Bt, acc[0][t], 0, 0, 0);
      acc[1][t] = __builtin_amdgcn_mfma_f32_16x16x32_bf16(A1, Bt, acc[1][t], 0, 0, 0);
    }
  }
  int which = n0 >> 9;
  int head = (n0 >> 6) & 7;
  float* dst = which == 0 ? Qo : (which == 1 ? Ko : Vo);
#pragma unroll
  for (int mt = 0; mt < 2; mt++) {
#pragma unroll
    for (int r = 0; r < 4; r++) {
      int m = mw + mt * 16 + quad * 4 + r;
      int bb = m >> 11, s = m & 2047;
      size_t rowoff = ((size_t)(bb * 8 + head) * 2048 + s) * 64;
#pragma unroll
      for (int t = 0; t < 4; t++) {
        int hd = t * 16 + l16;
        float v = acc[mt][t][r] + bias[n0 + hd];
        dst[rowoff + hd] = v;
        if (which == 0) Qh[rowoff + hd] = f2bf(v * 0.125f);
      }
    }
  }
}

// ---------------------------------------------------------------------------
// Kp (bf16 rows, B,NH,S,R) and Vp (fp32, B,NH,S,R) projections
// ---------------------------------------------------------------------------
__global__ __launch_bounds__(256) void kpvp_kernel(
    const float* __restrict__ K, const float* __restrict__ V,
    const float* __restrict__ Wkp, const float* __restrict__ bkp,
    const float* __restrict__ Wvp, const float* __restrict__ bvp,
    short* __restrict__ Kph, float* __restrict__ Vp) {
  int bh = blockIdx.x >> 4;            // 256 blocks: B*NH * (S/128)
  int k0 = (blockIdx.x & 15) * 128;
  int tid = threadIdx.x;
  __shared__ float tile[128][65];
  __shared__ float Wb[64][65];
  for (int i = tid; i < 128 * 64; i += 256)
    tile[i >> 6][i & 63] = K[(bh * 2048 + k0 + (i >> 6)) * 64 + (i & 63)];
  for (int i = tid; i < 4096; i += 256) Wb[i >> 6][i & 63] = Wkp[i];
  __syncthreads();
  {
    int kl = tid & 63, rbase = (tid >> 6) * 16;
    for (int half = 0; half < 2; half++) {
      int kk = kl + half * 64;
      int packed[8];
#pragma unroll
      for (int ri = 0; ri < 16; ri += 2) {
        float a0 = bkp[rbase + ri], a1 = bkp[rbase + ri + 1];
#pragma unroll 8
        for (int d = 0; d < 64; d++) {
          float t = tile[kk][d];
          a0 += t * Wb[rbase + ri][d];
          a1 += t * Wb[rbase + ri + 1][d];
        }
        packed[ri >> 1] = pack2bf(a0, a1);
      }
      int4* dst = (int4*)(Kph + (size_t)(bh * 2048 + k0 + kk) * 64 + rbase);
      dst[0] = make_int4(packed[0], packed[1], packed[2], packed[3]);
      dst[1] = make_int4(packed[4], packed[5], packed[6], packed[7]);
    }
  }
  __syncthreads();
  for (int i = tid; i < 128 * 64; i += 256)
    tile[i >> 6][i & 63] = V[(bh * 2048 + k0 + (i >> 6)) * 64 + (i & 63)];
  for (int i = tid; i < 4096; i += 256) Wb[i >> 6][i & 63] = Wvp[i];
  __syncthreads();
  {
    int r = tid & 63, kb = tid >> 6;
    for (int ri = 0; ri < 32; ri++) {
      int kk = kb + ri * 4;
      float acc = bvp[r];
#pragma unroll 8
      for (int d = 0; d < 64; d++) acc += tile[kk][d] * Wb[r][d];
      Vp[(bh * 2048 + k0 + kk) * 64 + r] = acc;
    }
  }
}

// ---------------------------------------------------------------------------
// local windowed attention: one wave per query
// ---------------------------------------------------------------------------
__global__ __launch_bounds__(256) void local_attn(
    const float* __restrict__ Q, const float* __restrict__ K,
    const float* __restrict__ V, float* __restrict__ ctxl) {
  int idx = blockIdx.x * 4 + (threadIdx.x >> 6);
  int lane = threadIdx.x & 63;
  int bh = idx >> 11;
  int s = idx & 2047;
  float qd = Q[idx * 64 + lane];
  float sc[5];
  bool ok[5];
#pragma unroll
  for (int j = 0; j < 5; j++) {
    int sj = s + j - 2;
    ok[j] = (sj >= 0 && sj < SS);
    float p = ok[j] ? qd * K[(bh * 2048 + sj) * 64 + lane] : 0.f;
    p += __shfl_xor(p, 1);  p += __shfl_xor(p, 2);  p += __shfl_xor(p, 4);
    p += __shfl_xor(p, 8);  p += __shfl_xor(p, 16); p += __shfl_xor(p, 32);
    sc[j] = p * 0.125f;
  }
  float m = -3.0e38f;
#pragma unroll
  for (int j = 0; j < 5; j++)
    if (ok[j]) m = fmaxf(m, sc[j]);
  float e[5], l = 0.f;
#pragma unroll
  for (int j = 0; j < 5; j++) {
    e[j] = ok[j] ? expf(sc[j] - m) : 0.f;
    l += e[j];
  }
  float inv = 1.f / l;
  float o = 0.f;
#pragma unroll
  for (int j = 0; j < 5; j++) {
    int sj = s + j - 2;
    if (ok[j]) o += e[j] * inv * V[(bh * 2048 + sj) * 64 + lane];
  }
  ctxl[idx * 64 + lane] = o;
}

// ---------------------------------------------------------------------------
// global sparse attention, 4-wave K-split edition. Block = one (bh,q-tile16);
// wave w scans keys [w*512,(w+1)*512) with per-(lane,reg) branch-free sorted
// top-8 (min/max pairs). Per-wave shfl merge -> sorted-16 per query -> LDS;
// 4-way sorted merge + softmax by 16 lanes; gather/projection by all 256.
// Output ctxc written bf16 for the MFMA Wo gemm.
// ---------------------------------------------------------------------------
__global__ __launch_bounds__(256) void global_attn(
    const short* __restrict__ Qh, const short* __restrict__ Kph,
    const float* __restrict__ Vp, const float* __restrict__ Wvp,
    const float* __restrict__ bvp, const float* __restrict__ ctxl,
    short* __restrict__ ctxcb) {
  int wid = blockIdx.x;                // 2048
  int bh = wid >> 7;
  int q0 = (wid & 127) * 16;
  int b = bh >> 3, hh = bh & 7;
  int tid = threadIdx.x;
  int wv = tid >> 6;
  int lane = tid & 63;
  int quad = lane >> 4, l16 = lane & 15;

  __shared__ unsigned mer[4][16][16];
  __shared__ float tw[16][17];
  __shared__ int   tix[16][17];
  __shared__ float spr[16][68];

  const short* qbase = Qh + (size_t)(bh * 2048 + q0 + l16) * 64 + quad * 8;
  bf16x8 a0 = *(const bf16x8*)qbase;
  bf16x8 a1 = *(const bf16x8*)(qbase + 32);

  const short* kbase =
      Kph + (size_t)(bh * 2048 + wv * 512 + l16) * 64 + quad * 8;
  bf16x8 b0 = *(const bf16x8*)kbase;
  bf16x8 b1 = *(const bf16x8*)(kbase + 32);

  unsigned e0[8], e1[8], e2[8], e3[8];
#pragma unroll
  for (int j = 0; j < 8; j++) { e0[j] = 0; e1[j] = 0; e2[j] = 0; e3[j] = 0; }

  auto insert8 = [&](unsigned (&er)[8], unsigned cand) {
    unsigned p = cand;
#pragma unroll
    for (int j = 0; j < 8; j++) {
      unsigned cur = er[j];
      unsigned hi = cur > p ? cur : p;   // v_max_u32
      p = cur > p ? p : cur;             // v_min_u32
      er[j] = hi;
    }
  };
  auto mkcand = [&](float s, int idxr) -> unsigned {
    unsigned u = __float_as_uint(s);
    u ^= ((unsigned)((int)u >> 31)) | 0x80000000u;
    return (u & 0xFFFFF800u) | (unsigned)idxr;
  };

  int idxbase = 2047 - (wv * 512 + l16);
#pragma unroll 1
  for (int g = 0; g < 32; g++) {
    int gn = (g + 1 < 32) ? g + 1 : 31;
    bf16x8 nb0 = *(const bf16x8*)(kbase + gn * 1024);
    bf16x8 nb1 = *(const bf16x8*)(kbase + gn * 1024 + 32);
    f32x4 C = {0.f, 0.f, 0.f, 0.f};
    C = __builtin_amdgcn_mfma_f32_16x16x32_bf16(a0, b0, C, 0, 0, 0);
    C = __builtin_amdgcn_mfma_f32_16x16x32_bf16(a1, b1, C, 0, 0, 0);
    int idxr = idxbase - (g << 4);
    insert8(e0, mkcand(C[0], idxr));
    insert8(e1, mkcand(C[1], idxr));
    insert8(e2, mkcand(C[2], idxr));
    insert8(e3, mkcand(C[3], idxr));
    b0 = nb0;
    b1 = nb1;
  }

  // per-wave merge: top-16 of this wave's 512 keys per query -> mer[wv][q][*]
  auto wmerge = [&](unsigned (&er)[8], int r) {
#pragma unroll
    for (int t = 0; t < 16; t++) {
      unsigned w = er[0];
#pragma unroll
      for (int mm = 1; mm <= 8; mm <<= 1) {
        unsigned o = (unsigned)__shfl_xor((int)w, mm);
        w = w > o ? w : o;
      }
      if (er[0] == w) {
#pragma unroll
        for (int j = 0; j < 7; j++) er[j] = er[j + 1];
        er[7] = 0;
      }
      if (l16 == r) mer[wv][quad * 4 + r][t] = w;
    }
  };
  wmerge(e0, 0);
  wmerge(e1, 1);
  wmerge(e2, 2);
  wmerge(e3, 3);
  __syncthreads();

  // final 4-way sorted merge + softmax: lane q handles query q
  if (tid < 16) {
    int q = tid;
    unsigned h0 = mer[0][q][0], h1 = mer[1][q][0];
    unsigned h2 = mer[2][q][0], h3 = mer[3][q][0];
    int p0 = 1, p1 = 1, p2 = 1, p3 = 1;
    float mval = 0.f, lsum = 0.f;
    float ev[16];
    int kit[16];
#pragma unroll
    for (int t = 0; t < 16; t++) {
      unsigned w01 = h0 > h1 ? h0 : h1;
      unsigned w23 = h2 > h3 ? h2 : h3;
      unsigned w = w01 > w23 ? w01 : w23;
      if (w == h0)      { h0 = p0 < 16 ? mer[0][q][p0] : 0u; p0++; }
      else if (w == h1) { h1 = p1 < 16 ? mer[1][q][p1] : 0u; p1++; }
      else if (w == h2) { h2 = p2 < 16 ? mer[2][q][p2] : 0u; p2++; }
      else              { h3 = p3 < 16 ? mer[3][q][p3] : 0u; p3++; }
      unsigned wvv = w & 0xFFFFF800u;
      unsigned uu = (w & 0x80000000u) ? (wvv ^ 0x80000000u) : ~wvv;
      float sv = __uint_as_float(uu);
      int ki = 2047 - (int)(w & 0x7FFu);
      if (t == 0) mval = sv;
      float ex = __expf(sv - mval);
      lsum += ex;
      ev[t] = ex;
      kit[t] = ki;
    }
    float inv = 1.f / lsum;
#pragma unroll
    for (int j = 0; j < 16; j++) {
      tw[q][j] = ev[j] * inv;
      tix[q][j] = kit[j];
    }
  }
  __syncthreads();

  // gather: 16 threads/query, 4 floats each
  {
    int q = tid >> 4, rl = (tid & 15) * 4;
    float ax = 0.f, ay = 0.f, az = 0.f, aw = 0.f;
#pragma unroll 4
    for (int j = 0; j < 16; j++) {
      float w = tw[q][j];
      const float* vrow = Vp + (size_t)(bh * 2048 + tix[q][j]) * 64 + rl;
      float4 v = *(const float4*)vrow;
      ax += w * v.x; ay += w * v.y; az += w * v.z; aw += w * v.w;
    }
    *(float4*)&spr[q][rl] = make_float4(ax, ay, az, aw);
  }
  __syncthreads();

  // projection sp @ Wvp^T + bvp, combine with local, write bf16 ctxc
  {
    int q = tid >> 4, jb = (tid & 15) * 4;
    float c0 = bvp[jb], c1 = bvp[jb + 1], c2 = bvp[jb + 2], c3 = bvp[jb + 3];
    for (int r = 0; r < 64; r += 4) {
      float4 sp4 = *(const float4*)&spr[q][r];
      float4 w0 = *(const float4*)(Wvp + (jb + 0) * 64 + r);
      float4 w1 = *(const float4*)(Wvp + (jb + 1) * 64 + r);
      float4 w2 = *(const float4*)(Wvp + (jb + 2) * 64 + r);
      float4 w3 = *(const float4*)(Wvp + (jb + 3) * 64 + r);
      c0 += sp4.x * w0.x + sp4.y * w0.y + sp4.z * w0.z + sp4.w * w0.w;
      c1 += sp4.x * w1.x + sp4.y * w1.y + sp4.z * w1.z + sp4.w * w1.w;
      c2 += sp4.x * w2.x + sp4.y * w2.y + sp4.z * w2.z + sp4.w * w2.w;
      c3 += sp4.x * w3.x + sp4.y * w3.y + sp4.z * w3.z + sp4.w * w3.w;
    }
    int s = q0 + q;
    const float* lrow = ctxl + (size_t)(bh * 2048 + s) * 64 + jb;
    float4 lv = *(const float4*)lrow;
    short4 o;
    o.x = f2bf(0.5f * (lv.x + c0));
    o.y = f2bf(0.5f * (lv.y + c1));
    o.z = f2bf(0.5f * (lv.z + c2));
    o.w = f2bf(0.5f * (lv.w + c3));
    *(short4*)(ctxcb + (size_t)(b * 2048 + s) * 512 + hh * 64 + jb) = o;
  }
}

// ---------------------------------------------------------------------------
// MFMA Wo gemm: out(4096x512) = ctxcb @ Wobf^T + bo + h (residual), fp32 out.
// ---------------------------------------------------------------------------
__global__ __launch_bounds__(256) void gemm_wo(
    const short* __restrict__ Abf, const short* __restrict__ Wbf,
    const float* __restrict__ bo, const float* __restrict__ h,
    float* __restrict__ outp) {
  int m0 = blockIdx.x * 128;
  int n0 = blockIdx.y * 64;
  int tid = threadIdx.x;
  int wvv = tid >> 6, lane = tid & 63;
  int quad = lane >> 4, l16 = lane & 15;
  int mw = m0 + wvv * 32;
  const short* ap0 = Abf + (size_t)(mw + l16) * 512 + quad * 8;
  const short* ap1 = ap0 + 16 * 512;
  const short* bp = Wbf + (size_t)(n0 + l16) * 512 + quad * 8;
  f32x4 acc[2][4] = {};
#pragma unroll 1
  for (int ks = 0; ks < 16; ks++) {
    int off = ks * 32;
    bf16x8 A0 = *(const bf16x8*)(ap0 + off);
    bf16x8 A1 = *(const bf16x8*)(ap1 + off);
#pragma unroll
    for (int t = 0; t < 4; t++) {
      bf16x8 Bt = *(const bf16x8*)(bp + t * 16 * 512 + off);
      acc[0][t] = __builtin_amdgcn_mfma_f32_16x16x32_bf16(A0, Bt, acc[0][t], 0, 0, 0);
      acc[1][t] = __builtin_amdgcn_mfma_f32_16x16x32_bf16(A1, Bt, acc[1][t], 0, 0, 0);
    }
  }
#pragma unroll
  for (int mt = 0; mt < 2; mt++) {
#pragma unroll
    for (int r = 0; r < 4; r++) {
      int m = mw + mt * 16 + quad * 4 + r;
#pragma unroll
      for (int t = 0; t < 4; t++) {
        int n = n0 + t * 16 + l16;
        outp[(size_t)m * 512 + n] =
            acc[mt][t][r] + bo[n] + h[(size_t)m * 512 + n];
      }
    }
  }
}

// ---------------------------------------------------------------------------
// layernorm in place on d_out, one block per row
// ---------------------------------------------------------------------------
__global__ __launch_bounds__(256) void ln_kernel(float* __restrict__ o,
                                                 const float* __restrict__ g,
                                                 const float* __restrict__ bb) {
  int row = blockIdx.x;
  int tid = threadIdx.x;
  float v0 = o[row * 512 + tid];
  float v1 = o[row * 512 + 256 + tid];
  float s = v0 + v1;
  float s2 = v0 * v0 + v1 * v1;
#pragma unroll
  for (int off = 1; off < 64; off <<= 1) {
    s += __shfl_xor(s, off);
    s2 += __shfl_xor(s2, off);
  }
  __shared__ float ps[4], ps2[4];
  int w = tid >> 6;
  if ((tid & 63) == 0) { ps[w] = s; ps2[w] = s2; }
  __syncthreads();
  float S = ps[0] + ps[1] + ps[2] + ps[3];
  float S2 = ps2[0] + ps2[1] + ps2[2] + ps2[3];
  float mu = S * (1.f / 512.f);
  float var = S2 * (1.f / 512.f) - mu * mu;
  float inv = rsqrtf(var + 1e-5f);
  o[row * 512 + tid] = (v0 - mu) * inv * g[tid] + bb[tid];
  o[row * 512 + 256 + tid] = (v1 - mu) * inv * g[tid + 256] + bb[tid + 256];
}

// ---------------------------------------------------------------------------
extern "C" void kernel_launch(void* const* d_in, const int* in_sizes, int n_in,
                              void* d_out, int out_size, void* d_ws,
                              size_t ws_size, hipStream_t stream) {
  const float* x   = (const float*)d_in[0];
  const float* w1  = (const float*)d_in[1];
  const float* b1  = (const float*)d_in[2];
  const float* w2  = (const float*)d_in[3];
  const float* b2  = (const float*)d_in[4];
  const float* w3  = (const float*)d_in[5];
  const float* b3  = (const float*)d_in[6];
  const float* Wq  = (const float*)d_in[7];
  const float* bq  = (const float*)d_in[8];
  const float* Wk  = (const float*)d_in[9];
  const float* bk  = (const float*)d_in[10];
  const float* Wv  = (const float*)d_in[11];
  const float* bv  = (const float*)d_in[12];
  const float* Wkp = (const float*)d_in[13];
  const float* bkp = (const float*)d_in[14];
  const float* Wvp = (const float*)d_in[15];
  const float* bvp = (const float*)d_in[16];
  const float* Wo  = (const float*)d_in[17];
  const float* bo  = (const float*)d_in[18];
  const float* lng = (const float*)d_in[19];
  const float* lnb = (const float*)d_in[20];

  float* ws     = (float*)d_ws;
  short* Wallbf = (short*)ws;              // 786432 shorts in 786432-float slot
  float* ball   = ws + 786432;             // 1536
  short* Wobf   = (short*)(ball + 1536);   // 262144 shorts in 262144-float slot
  float* h      = ball + 1536 + 262144;    // 2097152 floats each below
  float* Qb     = h + 2097152;
  float* Kb     = Qb + 2097152;
  float* Vb     = Kb + 2097152;
  float* bf16slot = Vb + 2097152;          // Kph + Qh (bf16)
  float* Vpb    = bf16slot + 2097152;
  float* ctxl   = Vpb + 2097152;
  float* cslot  = ctxl + 2097152;          // ctxcb + hbf (bf16)
  float* outF   = (float*)d_out;

  short* Kph   = (short*)bf16slot;
  short* Qh    = Kph + 2097152;
  short* ctxcb = (short*)cslot;
  short* hbf   = ctxcb + 2097152;

  prep_kernel<<<512, 256, 0, stream>>>(Wq, Wk, Wv, bq, bk, bv, Wo, Wallbf,
                                       ball, Wobf);
  conv_kernel<<<512, 256, 0, stream>>>(x, w1, b1, w2, b2, w3, b3, h, hbf);
  {
    dim3 g(32, 24);
    gemm_qkv<<<g, 256, 0, stream>>>(hbf, Wallbf, ball, Qb, Kb, Vb, Qh);
  }
  kpvp_kernel<<<256, 256, 0, stream>>>(Kb, Vb, Wkp, bkp, Wvp, bvp, Kph, Vpb);
  local_attn<<<8192, 256, 0, stream>>>(Qb, Kb, Vb, ctxl);
  global_attn<<<2048, 256, 0, stream>>>(Qh, Kph, Vpb, Wvp, bvp, ctxl, ctxcb);
  {
    dim3 g(32, 8);
    gemm_wo<<<g, 256, 0, stream>>>(ctxcb, Wobf, bo, h, outF);
  }
  ln_kernel<<<4096, 256, 0, stream>>>(outF, lng, lnb);
}